// Round 16
// baseline (540.282 us; speedup 1.0000x reference)
//
#include <hip/hip_runtime.h>

typedef __bf16 bf16x8 __attribute__((ext_vector_type(8)));
typedef float float4v __attribute__((ext_vector_type(4)));
typedef unsigned short ushort4v __attribute__((ext_vector_type(4)));
typedef unsigned short ushort8v __attribute__((ext_vector_type(8)));

#define K_D 512
#define K_S 50

__device__ __forceinline__ float b2f(unsigned short u) {
  union { unsigned int u32; float f; } v; v.u32 = ((unsigned int)u) << 16; return v.f;
}
__device__ __forceinline__ unsigned short f2b(float f) {
  __bf16 h = (__bf16)f;
  return __builtin_bit_cast(unsigned short, h);
}

// A/B fragment load from LDS stored [rows][E] bf16, XOR-swizzled (byte ^= (row&7)<<4)
__device__ __forceinline__ bf16x8 ldfrag(const unsigned short* buf, int E, int r0, int k0, int lane) {
  int row = r0 + (lane & 15);
  int kb = (k0 + ((lane >> 4) << 3)) << 1;
  return *(const bf16x8*)(buf + row * E + ((kb ^ ((row & 7) << 4)) >> 1));
}
// Variant with explicit swizzle mask (for short rows, e.g. V^T with 64B rows)
__device__ __forceinline__ bf16x8 ldfragm(const unsigned short* buf, int E, int r0, int k0,
                                          int lane, int mask) {
  int row = r0 + (lane & 15);
  int kb = (k0 + ((lane >> 4) << 3)) << 1;
  return *(const bf16x8*)(buf + row * E + ((kb ^ ((row & mask) << 4)) >> 1));
}

__device__ __forceinline__ float4v mfma16(bf16x8 a, bf16x8 b, float4v c) {
  return __builtin_amdgcn_mfma_f32_16x16x32_bf16(a, b, c, 0, 0, 0);
}

// Convert fp32 weight W[K][N] (row-major) into fragment-ordered bf16 tiles
__global__ void prep_weights(const float* __restrict__ src, unsigned short* __restrict__ dst,
                             int K, int N) {
  int KT = K >> 5;
  int total = (N >> 4) * KT * 64;
  int t = blockIdx.x * blockDim.x + threadIdx.x;
  if (t >= total) return;
  int l = t & 63;
  int kt = (t >> 6) % KT;
  int nt = (t >> 6) / KT;
  int kbase = kt * 32 + ((l >> 4) << 3);
  int col = nt * 16 + (l & 15);
  ushort8v o;
  #pragma unroll
  for (int j = 0; j < 8; ++j) o[j] = f2b(src[(size_t)(kbase + j) * N + col]);
  *(ushort8v*)(dst + (size_t)t * 8) = o;
}

__global__ void zero_meta(int* meta) { if (threadIdx.x < 2) meta[threadIdx.x] = 0; }

// Bucket items by mt class. Output order is atomic (non-stable) but each item is
// processed identically by the main kernel -> output deterministic.
__global__ void bucket(const int* __restrict__ lengths, int* __restrict__ lists,
                       int* __restrict__ meta) {
  int i = blockIdx.x * blockDim.x + threadIdx.x;
  if (i >= 4096) return;
  int mt = (lengths[i] + 16) >> 4;
  if (mt <= 2) { int p = atomicAdd(&meta[0], 1); lists[p] = i; }
  else         { int p = atomicAdd(&meta[1], 1); lists[4096 + p] = i; }
}

// Wave computes MT m-tiles x NT n-tiles.  SLOTS=2: two in-place B prefetch
// slots (consume-then-refill, no copies). APRE=1 also double-slots A (LDS).
template<int NT, int KS, int MT, int SLOTS, int APRE>
__device__ __forceinline__ void mmN(const unsigned short* Ab, int EA,
                                    const bf16x8* __restrict__ Wf, int wnb, int KT, int l,
                                    float4v* acc) {
  if constexpr (SLOTS == 2) {
    bf16x8 p0[NT], p1[NT];
    #pragma unroll
    for (int n = 0; n < NT; ++n) {
      p0[n] = Wf[(size_t)((wnb + n) * KT) * 64 + l];
      p1[n] = Wf[(size_t)((wnb + n) * KT + 1) * 64 + l];
    }
    bf16x8 a0[MT], a1[MT];
    if constexpr (APRE) {
      #pragma unroll
      for (int m = 0; m < MT; ++m) {
        a0[m] = ldfrag(Ab, EA, m * 16, 0, l);
        a1[m] = ldfrag(Ab, EA, m * 16, 32, l);
      }
    }
    #pragma unroll 1
    for (int kt = 0; kt < KS; kt += 2) {
      {
        if constexpr (!APRE) {
          #pragma unroll
          for (int m = 0; m < MT; ++m) a0[m] = ldfrag(Ab, EA, m * 16, kt * 32, l);
        }
        #pragma unroll
        for (int n = 0; n < NT; ++n) {
          #pragma unroll
          for (int m = 0; m < MT; ++m)
            acc[m * NT + n] = mfma16(a0[m], p0[n], acc[m * NT + n]);
        }
        if (kt + 2 < KS) {
          #pragma unroll
          for (int n = 0; n < NT; ++n)
            p0[n] = Wf[(size_t)((wnb + n) * KT + kt + 2) * 64 + l];
          if constexpr (APRE) {
            #pragma unroll
            for (int m = 0; m < MT; ++m) a0[m] = ldfrag(Ab, EA, m * 16, (kt + 2) * 32, l);
          }
        }
      }
      {
        if constexpr (!APRE) {
          #pragma unroll
          for (int m = 0; m < MT; ++m) a1[m] = ldfrag(Ab, EA, m * 16, (kt + 1) * 32, l);
        }
        #pragma unroll
        for (int n = 0; n < NT; ++n) {
          #pragma unroll
          for (int m = 0; m < MT; ++m)
            acc[m * NT + n] = mfma16(a1[m], p1[n], acc[m * NT + n]);
        }
        if (kt + 3 < KS) {
          #pragma unroll
          for (int n = 0; n < NT; ++n)
            p1[n] = Wf[(size_t)((wnb + n) * KT + kt + 3) * 64 + l];
          if constexpr (APRE) {
            #pragma unroll
            for (int m = 0; m < MT; ++m) a1[m] = ldfrag(Ab, EA, m * 16, (kt + 3) * 32, l);
          }
        }
      }
    }
  } else {
    bf16x8 bn[NT];
    #pragma unroll
    for (int n = 0; n < NT; ++n) bn[n] = Wf[(size_t)((wnb + n) * KT) * 64 + l];
    #pragma unroll 1
    for (int kt = 0; kt < KS; ++kt) {
      bf16x8 a[MT];
      #pragma unroll
      for (int m = 0; m < MT; ++m) a[m] = ldfrag(Ab, EA, m * 16, kt * 32, l);
      #pragma unroll
      for (int n = 0; n < NT; ++n) {
        #pragma unroll
        for (int m = 0; m < MT; ++m)
          acc[m * NT + n] = mfma16(a[m], bn[n], acc[m * NT + n]);
      }
      if (kt + 1 < KS) {
        #pragma unroll
        for (int n = 0; n < NT; ++n)
          bn[n] = Wf[(size_t)((wnb + n) * KT + kt + 1) * 64 + l];
      }
    }
  }
}

// LayerNorm over rows {widx, widx+STRIDE, ...} < nrows of sXbuf [rows][512] bf16.
template<int STRIDE>
__device__ __forceinline__ void ln_pass(unsigned short* sXbuf, const float* __restrict__ g,
                                        const float* __restrict__ bb, int widx, int l, int nrows) {
  float gv[8], bv[8];
  {
    const float4* g4 = (const float4*)(g + l * 8);
    const float4* b4 = (const float4*)(bb + l * 8);
    float4 a0 = g4[0], a1 = g4[1], c0 = b4[0], c1 = b4[1];
    gv[0] = a0.x; gv[1] = a0.y; gv[2] = a0.z; gv[3] = a0.w;
    gv[4] = a1.x; gv[5] = a1.y; gv[6] = a1.z; gv[7] = a1.w;
    bv[0] = c0.x; bv[1] = c0.y; bv[2] = c0.z; bv[3] = c0.w;
    bv[4] = c1.x; bv[5] = c1.y; bv[6] = c1.z; bv[7] = c1.w;
  }
  #pragma unroll 1
  for (int r = widx; r < nrows; r += STRIDE) {
    int e = r * 512 + (((l << 4) ^ ((r & 7) << 4)) >> 1);  // cols l*8..l*8+7
    ushort8v x = *(const ushort8v*)(sXbuf + e);
    float v[8];
    float s = 0.f, s2 = 0.f;
    #pragma unroll
    for (int j = 0; j < 8; ++j) { v[j] = b2f(x[j]); s += v[j]; s2 += v[j] * v[j]; }
    #pragma unroll
    for (int off = 1; off < 64; off <<= 1) { s += __shfl_xor(s, off); s2 += __shfl_xor(s2, off); }
    float mu = s * (1.f / 512.f);
    float var = s2 * (1.f / 512.f) - mu * mu;
    float rstd = rsqrtf(var + 1e-6f);
    ushort8v o;
    #pragma unroll
    for (int j = 0; j < 8; ++j) o[j] = f2b((v[j] - mu) * rstd * gv[j] + bv[j]);
    *(ushort8v*)(sXbuf + e) = o;
  }
}

// Fused QKV sub-pass for the paired-small body: one n-tile triplet, MT=2,
// single-slot consume-then-refill. Writes Q (scaled), K; returns V acc.
__device__ __forceinline__ void qkv_pass(const unsigned short* sX,
                                         const unsigned short* wqkvf, int nt, int l,
                                         unsigned short* sQ, unsigned short* sK,
                                         const float* __restrict__ bqkv, float4v accV[2]) {
  const bf16x8* Wf = (const bf16x8*)wqkvf;
  float4v accQ[2], accK[2];
  accQ[0] = (float4v){0.f,0.f,0.f,0.f}; accQ[1] = accQ[0];
  accK[0] = accQ[0]; accK[1] = accQ[0];
  accV[0] = accQ[0]; accV[1] = accQ[0];
  const size_t bQ = (size_t)(nt) * 16 * 64 + l;        // KT=16
  const size_t bK = (size_t)(16 + nt) * 16 * 64 + l;
  const size_t bV = (size_t)(32 + nt) * 16 * 64 + l;
  bf16x8 q0 = Wf[bQ], k0 = Wf[bK], v0 = Wf[bV];
  #pragma unroll 1
  for (int kt = 0; kt < 16; ++kt) {
    bf16x8 a0 = ldfrag(sX, 512, 0, kt * 32, l);
    bf16x8 a1 = ldfrag(sX, 512, 16, kt * 32, l);
    accQ[0] = mfma16(a0, q0, accQ[0]); accQ[1] = mfma16(a1, q0, accQ[1]);
    accK[0] = mfma16(a0, k0, accK[0]); accK[1] = mfma16(a1, k0, accK[1]);
    accV[0] = mfma16(a0, v0, accV[0]); accV[1] = mfma16(a1, v0, accV[1]);
    if (kt + 1 < 16) {
      q0 = Wf[bQ + (size_t)(kt + 1) * 64];
      k0 = Wf[bK + (size_t)(kt + 1) * 64];
      v0 = Wf[bV + (size_t)(kt + 1) * 64];
    }
  }
  const float qscale = 0.044194173824159216f;  // 1/sqrt(512)
  int col = nt * 16 + (l & 15);
  float biasQ = bqkv[col];
  float biasK = bqkv[256 + col];
  #pragma unroll
  for (int m = 0; m < 2; ++m) {
    int r0 = m * 16 + ((l >> 4) << 2);
    #pragma unroll
    for (int j = 0; j < 4; ++j) {
      int r = r0 + j;
      sQ[r * 256 + (((col << 1) ^ ((r & 7) << 4)) >> 1)] = f2b((accQ[m][j] + biasQ) * qscale);
      sK[r * 256 + (((col << 1) ^ ((r & 7) << 4)) >> 1)] = f2b(accK[m][j] + biasK);
    }
  }
}

// Paired-small body: one item per 8-wave group (ws 0..7, ht 0..511), MT=2
// padded (mt=1 items just have more zero rows). 76KB LDS half.
// Per-phase passes merged (NT=2 FF1, NT=4 FF2/Wo) to cut serial ramp count.
__device__ __forceinline__ void small_body(
    unsigned short* sX, unsigned short* sQ, unsigned short* sK,
    float* sS, unsigned short* sP,
    const float* __restrict__ embed, const int* __restrict__ gidx,
    const float* __restrict__ b1, const float* __restrict__ b2,
    const float* __restrict__ ln1g, const float* __restrict__ ln1b,
    const float* __restrict__ bqkv, const float* __restrict__ bo,
    const float* __restrict__ ln2g, const float* __restrict__ ln2b,
    const unsigned short* __restrict__ w1f, const unsigned short* __restrict__ w2f,
    const unsigned short* __restrict__ wqkvf, const unsigned short* __restrict__ wof,
    float* __restrict__ out, int ht, int ws, int l, int item, int len) {

  // ---- phase 0: gather rows 0..31 (zeros beyond len) ----
  {
    int sub = ht >> 7;           // 0..3
    int c0 = (ht & 127) << 2;
    #pragma unroll 2
    for (int it = 0; it < 8; ++it) {
      int r = it * 4 + sub;
      float4 v = make_float4(0.f, 0.f, 0.f, 0.f);
      if (r <= len) {
        int row = gidx[item * K_S + r];
        v = *(const float4*)(embed + (size_t)row * K_D + c0);
      }
      ushort4v o;
      o[0] = f2b(v.x); o[1] = f2b(v.y); o[2] = f2b(v.z); o[3] = f2b(v.w);
      *(ushort4v*)(sX + r * 512 + (((c0 << 1) ^ ((r & 7) << 4)) >> 1)) = o;
    }
  }
  __syncthreads();

  // ---- phase 1: FF1, one NT=2 pass (2 n-tiles per wave) ----
  {
    float4v acc[4];
    #pragma unroll
    for (int i = 0; i < 4; ++i) acc[i] = (float4v){0.f,0.f,0.f,0.f};
    mmN<2, 16, 2, 2, 1>(sX, 512, (const bf16x8*)w1f, ws * 2, 16, l, acc);
    #pragma unroll
    for (int n = 0; n < 2; ++n) {
      int col = (ws * 2 + n) * 16 + (l & 15);
      float bias = b1[col];
      #pragma unroll
      for (int m = 0; m < 2; ++m) {
        int r0 = m * 16 + ((l >> 4) << 2);
        #pragma unroll
        for (int j = 0; j < 4; ++j) {
          int r = r0 + j;
          sQ[r * 256 + (((col << 1) ^ ((r & 7) << 4)) >> 1)] = f2b(fmaxf(acc[m * 2 + n][j] + bias, 0.f));
        }
      }
    }
  }
  __syncthreads();

  // ---- phase 2: FF2, one NT=4 single-slot pass (4 n-tiles per wave) ----
  {
    float4v acc[8];
    #pragma unroll
    for (int i = 0; i < 8; ++i) acc[i] = (float4v){0.f,0.f,0.f,0.f};
    mmN<4, 8, 2, 1, 0>(sQ, 256, (const bf16x8*)w2f, ws * 4, 8, l, acc);
    #pragma unroll
    for (int n = 0; n < 4; ++n) {
      int col = (ws * 4 + n) * 16 + (l & 15);
      float bias = b2[col];
      #pragma unroll
      for (int m = 0; m < 2; ++m) {
        int r0 = m * 16 + ((l >> 4) << 2);
        #pragma unroll
        for (int j = 0; j < 4; ++j) {
          int r = r0 + j;
          int e = r * 512 + (((col << 1) ^ ((r & 7) << 4)) >> 1);
          sX[e] = f2b(acc[m * 4 + n][j] + bias + b2f(sX[e]));
        }
      }
    }
  }
  __syncthreads();
  ln_pass<8>(sX, ln1g, ln1b, ws, l, 32);
  __syncthreads();

  // ---- phase 3: fused QKV (two triplet sub-passes); V kept in regs ----
  float4v accV0[2], accV1[2];
  qkv_pass(sX, wqkvf, ws * 2 + 0, l, sQ, sK, bqkv, accV0);
  qkv_pass(sX, wqkvf, ws * 2 + 1, l, sQ, sK, bqkv, accV1);
  __syncthreads();

  // ---- phase 4: scores (waves 0..3), tile (ws>>1, ws&1) ----
  if (ws < 4) {
    int m0 = (ws >> 1) * 16, n0 = (ws & 1) * 16;
    float4v acc = (float4v){0.f,0.f,0.f,0.f};
    bf16x8 b0 = ldfrag(sK, 256, n0, 0, l),  aq0 = ldfrag(sQ, 256, m0, 0, l);
    bf16x8 b1 = ldfrag(sK, 256, n0, 32, l), aq1 = ldfrag(sQ, 256, m0, 32, l);
    #pragma unroll 1
    for (int kt = 0; kt < 8; kt += 2) {
      acc = mfma16(aq0, b0, acc);
      if (kt + 2 < 8) { b0 = ldfrag(sK, 256, n0, (kt + 2) * 32, l); aq0 = ldfrag(sQ, 256, m0, (kt + 2) * 32, l); }
      acc = mfma16(aq1, b1, acc);
      if (kt + 3 < 8) { b1 = ldfrag(sK, 256, n0, (kt + 3) * 32, l); aq1 = ldfrag(sQ, 256, m0, (kt + 3) * 32, l); }
    }
    int col = n0 + (l & 15);
    int r0 = m0 + ((l >> 4) << 2);
    #pragma unroll
    for (int j = 0; j < 4; ++j) {
      int r = r0 + j;
      sS[r * 64 + (((col << 2) ^ ((r & 7) << 4)) >> 2)] = acc[j];
    }
  }
  __syncthreads();

  // ---- phase 5: softmax (4 rows/wave) -> sP; V^T -> sK (KVP=32, SWM=3) ----
  {
    const bool valid = (l <= len);
    #pragma unroll 1
    for (int r = ws; r < 32; r += 8) {
      float s = valid ? sS[r * 64 + (((l << 2) ^ ((r & 7) << 4)) >> 2)] : -1e30f;
      float mx = s;
      #pragma unroll
      for (int off = 1; off < 64; off <<= 1) mx = fmaxf(mx, __shfl_xor(mx, off));
      float p = valid ? __expf(s - mx) : 0.f;
      float sum = p;
      #pragma unroll
      for (int off = 1; off < 64; off <<= 1) sum += __shfl_xor(sum, off);
      sP[r * 64 + (((l << 1) ^ ((r & 7) << 4)) >> 1)] = f2b(p / sum);
    }
    #pragma unroll
    for (int p = 0; p < 2; ++p) {
      int c = (ws * 2 + p) * 16 + (l & 15);
      float biasV = bqkv[512 + c];
      const float4v* aV = p ? accV1 : accV0;
      #pragma unroll
      for (int m = 0; m < 2; ++m) {
        int r0 = m * 16 + ((l >> 4) << 2);
        ushort4v o;
        #pragma unroll
        for (int j = 0; j < 4; ++j) o[j] = f2b(aV[m][j] + biasV);
        *(ushort4v*)(sK + c * 32 + (((r0 << 1) ^ ((c & 3) << 4)) >> 1)) = o;
      }
    }
  }
  __syncthreads();

  // ---- phase 7: ctx = P @ V (2 n-tiles, merged: P loaded once) -> sQ ----
  {
    bf16x8 pa0 = ldfrag(sP, 64, 0, 0, l);
    bf16x8 pa1 = ldfrag(sP, 64, 16, 0, l);
    bf16x8 bf0 = ldfragm(sK, 32, (ws * 2 + 0) * 16, 0, l, 3);
    bf16x8 bf1 = ldfragm(sK, 32, (ws * 2 + 1) * 16, 0, l, 3);
    float4v z = (float4v){0.f,0.f,0.f,0.f};
    float4v c00 = mfma16(pa0, bf0, z), c10 = mfma16(pa1, bf0, z);
    float4v c01 = mfma16(pa0, bf1, z), c11 = mfma16(pa1, bf1, z);
    #pragma unroll
    for (int p = 0; p < 2; ++p) {
      int col = (ws * 2 + p) * 16 + (l & 15);
      #pragma unroll
      for (int m = 0; m < 2; ++m) {
        const float4v& cc = p ? (m ? c11 : c01) : (m ? c10 : c00);
        int r0 = m * 16 + ((l >> 4) << 2);
        #pragma unroll
        for (int j = 0; j < 4; ++j) {
          int r = r0 + j;
          sQ[r * 256 + (((col << 1) ^ ((r & 7) << 4)) >> 1)] = f2b(cc[j]);
        }
      }
    }
  }
  __syncthreads();

  // ---- phase 8: Wo, one NT=4 single-slot pass + residual ----
  {
    float4v acc[8];
    #pragma unroll
    for (int i = 0; i < 8; ++i) acc[i] = (float4v){0.f,0.f,0.f,0.f};
    mmN<4, 8, 2, 1, 0>(sQ, 256, (const bf16x8*)wof, ws * 4, 8, l, acc);
    #pragma unroll
    for (int n = 0; n < 4; ++n) {
      int col = (ws * 4 + n) * 16 + (l & 15);
      float bias = bo[col];
      #pragma unroll
      for (int m = 0; m < 2; ++m) {
        int r0 = m * 16 + ((l >> 4) << 2);
        #pragma unroll
        for (int j = 0; j < 4; ++j) {
          int r = r0 + j;
          int e = r * 512 + (((col << 1) ^ ((r & 7) << 4)) >> 1);
          sX[e] = f2b(acc[m * 4 + n][j] + bias + b2f(sX[e]));
        }
      }
    }
  }
  __syncthreads();
  ln_pass<8>(sX, ln2g, ln2b, ws, l, 32);
  __syncthreads();

  // ---- phase 9: masked mean pool (one col per thread, serial rows) ----
  {
    float sum = 0.f;
    for (int s = 0; s <= len; ++s)
      sum += b2f(sX[s * 512 + (((ht << 1) ^ ((s & 7) << 4)) >> 1)]);
    out[(size_t)item * K_D + ht] = sum / (float)(len + 1);
  }
}

// R11-structure big body (MT=3/4), full 152KB layout.
template<int MT>
__device__ __forceinline__ void big_body(
    unsigned short* sX, unsigned short* sQ, unsigned short* sK,
    float* sS, unsigned short* sP,
    const float* __restrict__ embed, const int* __restrict__ gidx,
    const float* __restrict__ b1, const float* __restrict__ b2,
    const float* __restrict__ ln1g, const float* __restrict__ ln1b,
    const float* __restrict__ bqkv, const float* __restrict__ bo,
    const float* __restrict__ ln2g, const float* __restrict__ ln2b,
    const unsigned short* __restrict__ w1f, const unsigned short* __restrict__ w2f,
    const unsigned short* __restrict__ wqkvf, const unsigned short* __restrict__ wof,
    float* __restrict__ out, int tid, int w, int l, int item, int len) {

  constexpr int ROWS = 16 * MT;
  constexpr int S2 = (MT <= 3) ? 2 : 1;
  constexpr int AP1 = (MT <= 3) ? 1 : 0;

  {
    const int sub = tid >> 7;
    const int c0 = (tid & 127) << 2;
    #pragma unroll 2
    for (int it = 0; it < 2 * MT; ++it) {
      int r = it * 8 + sub;
      float4 v = make_float4(0.f, 0.f, 0.f, 0.f);
      if (r <= len) {
        int row = gidx[item * K_S + r];
        v = *(const float4*)(embed + (size_t)row * K_D + c0);
      }
      ushort4v o;
      o[0] = f2b(v.x); o[1] = f2b(v.y); o[2] = f2b(v.z); o[3] = f2b(v.w);
      *(ushort4v*)(sX + r * 512 + (((c0 << 1) ^ ((r & 7) << 4)) >> 1)) = o;
    }
  }
  __syncthreads();

  {
    float4v acc[MT];
    #pragma unroll
    for (int i = 0; i < MT; ++i) acc[i] = (float4v){0.f,0.f,0.f,0.f};
    mmN<1, 16, MT, 2, AP1>(sX, 512, (const bf16x8*)w1f, w, 16, l, acc);
    int col = w * 16 + (l & 15);
    float bias = b1[col];
    #pragma unroll
    for (int m = 0; m < MT; ++m) {
      int r0 = m * 16 + ((l >> 4) << 2);
      #pragma unroll
      for (int j = 0; j < 4; ++j) {
        int r = r0 + j;
        sQ[r * 256 + (((col << 1) ^ ((r & 7) << 4)) >> 1)] = f2b(fmaxf(acc[m][j] + bias, 0.f));
      }
    }
  }
  __syncthreads();

  {
    float4v acc[2 * MT];
    #pragma unroll
    for (int i = 0; i < 2 * MT; ++i) acc[i] = (float4v){0.f,0.f,0.f,0.f};
    mmN<2, 8, MT, S2, 0>(sQ, 256, (const bf16x8*)w2f, w * 2, 8, l, acc);
    #pragma unroll
    for (int n = 0; n < 2; ++n) {
      int col = (w * 2 + n) * 16 + (l & 15);
      float bias = b2[col];
      #pragma unroll
      for (int m = 0; m < MT; ++m) {
        int r0 = m * 16 + ((l >> 4) << 2);
        #pragma unroll
        for (int j = 0; j < 4; ++j) {
          int r = r0 + j;
          int e = r * 512 + (((col << 1) ^ ((r & 7) << 4)) >> 1);
          sX[e] = f2b(acc[m * 2 + n][j] + bias + b2f(sX[e]));
        }
      }
    }
  }
  __syncthreads();
  ln_pass<16>(sX, ln1g, ln1b, w, l, ROWS);
  __syncthreads();

  {
    const bf16x8* Wf = (const bf16x8*)wqkvf;
    float4v accQ[MT], accK[MT];
    #pragma unroll
    for (int i = 0; i < MT; ++i) {
      accQ[i] = (float4v){0.f,0.f,0.f,0.f};
      accK[i] = (float4v){0.f,0.f,0.f,0.f};
    }
    const size_t baseQ = (size_t)(w) * 16 * 64 + l;
    const size_t baseK = (size_t)(16 + w) * 16 * 64 + l;
    bf16x8 q0 = Wf[baseQ], k0 = Wf[baseK];
    #pragma unroll 1
    for (int kt = 0; kt < 16; ++kt) {
      bf16x8 a[MT];
      #pragma unroll
      for (int m = 0; m < MT; ++m) a[m] = ldfrag(sX, 512, m * 16, kt * 32, l);
      #pragma unroll
      for (int m = 0; m < MT; ++m) accQ[m] = mfma16(a[m], q0, accQ[m]);
      #pragma unroll
      for (int m = 0; m < MT; ++m) accK[m] = mfma16(a[m], k0, accK[m]);
      if (kt + 1 < 16) {
        q0 = Wf[baseQ + (size_t)(kt + 1) * 64];
        k0 = Wf[baseK + (size_t)(kt + 1) * 64];
      }
    }
    const float qscale = 0.044194173824159216f;
    int col = w * 16 + (l & 15);
    float biasQ = bqkv[col];
    float biasK = bqkv[256 + col];
    #pragma unroll
    for (int m = 0; m < MT; ++m) {
      int r0 = m * 16 + ((l >> 4) << 2);
      #pragma unroll
      for (int j = 0; j < 4; ++j) {
        int r = r0 + j;
        sQ[r * 256 + (((col << 1) ^ ((r & 7) << 4)) >> 1)] = f2b((accQ[m][j] + biasQ) * qscale);
        sK[r * 256 + (((col << 1) ^ ((r & 7) << 4)) >> 1)] = f2b(accK[m][j] + biasK);
      }
    }
  }
  __syncthreads();

  if ((w >> 2) < MT) {
    float4v acc = (float4v){0.f,0.f,0.f,0.f};
    int n0 = (w & 3) * 16;
    int m0 = (w >> 2) * 16;
    bf16x8 b0 = ldfrag(sK, 256, n0, 0, l),  aq0 = ldfrag(sQ, 256, m0, 0, l);
    bf16x8 b1 = ldfrag(sK, 256, n0, 32, l), aq1 = ldfrag(sQ, 256, m0, 32, l);
    #pragma unroll 1
    for (int kt = 0; kt < 8; kt += 2) {
      acc = mfma16(aq0, b0, acc);
      if (kt + 2 < 8) { b0 = ldfrag(sK, 256, n0, (kt + 2) * 32, l); aq0 = ldfrag(sQ, 256, m0, (kt + 2) * 32, l); }
      acc = mfma16(aq1, b1, acc);
      if (kt + 3 < 8) { b1 = ldfrag(sK, 256, n0, (kt + 3) * 32, l); aq1 = ldfrag(sQ, 256, m0, (kt + 3) * 32, l); }
    }
    int col = n0 + (l & 15);
    int r0 = m0 + ((l >> 4) << 2);
    #pragma unroll
    for (int j = 0; j < 4; ++j) {
      int r = r0 + j;
      sS[r * 64 + (((col << 2) ^ ((r & 7) << 4)) >> 2)] = acc[j];
    }
  }
  float4v accV[MT];
  {
    #pragma unroll
    for (int i = 0; i < MT; ++i) accV[i] = (float4v){0.f,0.f,0.f,0.f};
    mmN<1, 16, MT, 2, AP1>(sX, 512, (const bf16x8*)wqkvf, 32 + w, 16, l, accV);
  }
  __syncthreads();

  {
    const bool valid = (l <= len);
    #pragma unroll 1
    for (int r = w; r < ROWS; r += 16) {
      float s = valid ? sS[r * 64 + (((l << 2) ^ ((r & 7) << 4)) >> 2)] : -1e30f;
      float mx = s;
      #pragma unroll
      for (int off = 1; off < 64; off <<= 1) mx = fmaxf(mx, __shfl_xor(mx, off));
      float p = valid ? __expf(s - mx) : 0.f;
      float sum = p;
      #pragma unroll
      for (int off = 1; off < 64; off <<= 1) sum += __shfl_xor(sum, off);
      sP[r * 64 + (((l << 1) ^ ((r & 7) << 4)) >> 1)] = f2b(p / sum);
    }
    int c = w * 16 + (l & 15);
    float biasV = bqkv[512 + c];
    #pragma unroll
    for (int m = 0; m < MT; ++m) {
      int r0 = m * 16 + ((l >> 4) << 2);
      ushort4v o;
      #pragma unroll
      for (int j = 0; j < 4; ++j) o[j] = f2b(accV[m][j] + biasV);
      *(ushort4v*)(sK + c * 64 + (((r0 << 1) ^ ((c & 7) << 4)) >> 1)) = o;
    }
    #pragma unroll
    for (int m = MT; m < 4; ++m) {
      int r0 = m * 16 + ((l >> 4) << 2);
      ushort4v o; o[0] = 0; o[1] = 0; o[2] = 0; o[3] = 0;
      *(ushort4v*)(sK + c * 64 + (((r0 << 1) ^ ((c & 7) << 4)) >> 1)) = o;
    }
  }
  __syncthreads();

  {
    float4v acc[MT];
    #pragma unroll
    for (int i = 0; i < MT; ++i) acc[i] = (float4v){0.f,0.f,0.f,0.f};
    #pragma unroll
    for (int kt = 0; kt < 2; ++kt) {
      bf16x8 bfr = ldfragm(sK, 64, w * 16, kt * 32, l, 7);
      #pragma unroll
      for (int m = 0; m < MT; ++m) {
        bf16x8 a = ldfrag(sP, 64, m * 16, kt * 32, l);
        acc[m] = mfma16(a, bfr, acc[m]);
      }
    }
    int col = w * 16 + (l & 15);
    #pragma unroll
    for (int m = 0; m < MT; ++m) {
      int r0 = m * 16 + ((l >> 4) << 2);
      #pragma unroll
      for (int j = 0; j < 4; ++j) {
        int r = r0 + j;
        sQ[r * 256 + (((col << 1) ^ ((r & 7) << 4)) >> 1)] = f2b(acc[m][j]);
      }
    }
  }
  __syncthreads();

  {
    float4v acc[2 * MT];
    #pragma unroll
    for (int i = 0; i < 2 * MT; ++i) acc[i] = (float4v){0.f,0.f,0.f,0.f};
    mmN<2, 8, MT, S2, 0>(sQ, 256, (const bf16x8*)wof, w * 2, 8, l, acc);
    #pragma unroll
    for (int n = 0; n < 2; ++n) {
      int col = (w * 2 + n) * 16 + (l & 15);
      float bias = bo[col];
      #pragma unroll
      for (int m = 0; m < MT; ++m) {
        int r0 = m * 16 + ((l >> 4) << 2);
        #pragma unroll
        for (int j = 0; j < 4; ++j) {
          int r = r0 + j;
          int e = r * 512 + (((col << 1) ^ ((r & 7) << 4)) >> 1);
          sX[e] = f2b(acc[m * 2 + n][j] + bias + b2f(sX[e]));
        }
      }
    }
  }
  __syncthreads();
  ln_pass<16>(sX, ln2g, ln2b, w, l, ROWS);
  __syncthreads();

  {
    int col = tid & 511;
    int half = tid >> 9;
    float sum = 0.f;
    for (int s = half; s <= len; s += 2)
      sum += b2f(sX[s * 512 + (((col << 1) ^ ((s & 7) << 4)) >> 1)]);
    if (half) sS[col] = sum;
    __syncthreads();
    if (!half) out[(size_t)item * K_D + col] = (sum + sS[col]) / (float)(len + 1);
  }
}

__global__ __launch_bounds__(1024, 4)
void fused_all(
    const float* __restrict__ embed, const int* __restrict__ gidx,
    const int* __restrict__ lengths,
    const float* __restrict__ b1, const float* __restrict__ b2,
    const float* __restrict__ ln1g, const float* __restrict__ ln1b,
    const float* __restrict__ bqkv, const float* __restrict__ bo,
    const float* __restrict__ ln2g, const float* __restrict__ ln2b,
    const unsigned short* __restrict__ w1f, const unsigned short* __restrict__ w2f,
    const unsigned short* __restrict__ wqkvf, const unsigned short* __restrict__ wof,
    const int* __restrict__ lists, const int* __restrict__ meta,
    float* __restrict__ out) {
  __shared__ unsigned char lds[155648];

  const int tid = (int)threadIdx.x;
  const int w = tid >> 6;
  const int l = tid & 63;
  const int j = (int)blockIdx.x;
  const int nsmall = meta[0];
  const int nbig = meta[1];

  if (j < 2048) {
    // paired-small region: items lists[2j], lists[2j+1]
    if (2 * j >= nsmall) return;
    int i0 = lists[2 * j];
    int i1 = (2 * j + 1 < nsmall) ? lists[2 * j + 1] : i0;  // dup: benign re-write
    int h = w >> 3;
    int ws = w & 7;
    int ht = ws * 64 + l;
    int item = h ? i1 : i0;
    int len = lengths[item];
    size_t base = (size_t)h * 77824;
    unsigned short* sX = (unsigned short*)(lds + base);
    unsigned short* sQ = (unsigned short*)(lds + base + 32768);
    unsigned short* sK = (unsigned short*)(lds + base + 49152);
    float* sS = (float*)(lds + base + 65536);
    unsigned short* sP = (unsigned short*)(lds + base + 73728);
    small_body(sX, sQ, sK, sS, sP, embed, gidx, b1, b2, ln1g, ln1b, bqkv, bo,
               ln2g, ln2b, w1f, w2f, wqkvf, wof, out, ht, ws, l, item, len);
  } else {
    int bi = j - 2048;
    if (bi >= nbig) return;
    int item = lists[4096 + bi];
    int len = lengths[item];
    int mt = (len + 16) >> 4;
    unsigned short* sX = (unsigned short*)lds;
    unsigned short* sQ = (unsigned short*)(lds + 65536);
    unsigned short* sK = (unsigned short*)(lds + 98304);
    float* sS = (float*)(lds + 131072);
    unsigned short* sP = (unsigned short*)(lds + 147456);
    if (mt == 3)
      big_body<3>(sX, sQ, sK, sS, sP, embed, gidx, b1, b2, ln1g, ln1b, bqkv, bo,
                  ln2g, ln2b, w1f, w2f, wqkvf, wof, out, tid, w, l, item, len);
    else
      big_body<4>(sX, sQ, sK, sS, sP, embed, gidx, b1, b2, ln1g, ln1b, bqkv, bo,
                  ln2g, ln2b, w1f, w2f, wqkvf, wof, out, tid, w, l, item, len);
  }
}

extern "C" void kernel_launch(void* const* d_in, const int* in_sizes, int n_in,
                              void* d_out, int out_size, void* d_ws, size_t ws_size,
                              hipStream_t stream) {
  (void)in_sizes; (void)n_in; (void)out_size; (void)ws_size;
  const float* embed = (const float*)d_in[0];
  const int* idx = (const int*)d_in[1];
  const int* lengths = (const int*)d_in[2];
  const float* W1 = (const float*)d_in[3];
  const float* b1 = (const float*)d_in[4];
  const float* W2 = (const float*)d_in[5];
  const float* b2 = (const float*)d_in[6];
  const float* ln1g = (const float*)d_in[7];
  const float* ln1b = (const float*)d_in[8];
  const float* Wqkv = (const float*)d_in[9];
  const float* bqkv = (const float*)d_in[10];
  const float* Wo = (const float*)d_in[11];
  const float* bo = (const float*)d_in[12];
  const float* ln2g = (const float*)d_in[13];
  const float* ln2b = (const float*)d_in[14];

  unsigned short* ws = (unsigned short*)d_ws;
  unsigned short* w1f = ws;                 // 131072 bf16
  unsigned short* w2f = ws + 131072;        // 131072
  unsigned short* wqkvf = ws + 262144;      // 393216
  unsigned short* wof = ws + 655360;        // 131072  -> ends at 786432
  int* lists = (int*)(ws + 786432);         // 8192 ints
  int* meta = lists + 8192;                 // 2 ints

  prep_weights<<<64, 256, 0, stream>>>(W1, w1f, 512, 256);
  prep_weights<<<64, 256, 0, stream>>>(W2, w2f, 256, 512);
  prep_weights<<<192, 256, 0, stream>>>(Wqkv, wqkvf, 512, 768);
  prep_weights<<<64, 256, 0, stream>>>(Wo, wof, 256, 512);
  zero_meta<<<1, 64, 0, stream>>>(meta);
  bucket<<<16, 256, 0, stream>>>(lengths, lists, meta);

  fused_all<<<6144, 1024, 0, stream>>>(embed, idx, lengths, b1, b2, ln1g, ln1b,
                                       bqkv, bo, ln2g, ln2b, w1f, w2f, wqkvf, wof,
                                       lists, meta, (float*)d_out);
}

// Round 17
// 499.594 us; speedup vs baseline: 1.0814x; 1.0814x over previous
//
#include <hip/hip_runtime.h>

typedef __bf16 bf16x8 __attribute__((ext_vector_type(8)));
typedef float float4v __attribute__((ext_vector_type(4)));
typedef unsigned short ushort4v __attribute__((ext_vector_type(4)));
typedef unsigned short ushort8v __attribute__((ext_vector_type(8)));

#define K_D 512
#define K_S 50

__device__ __forceinline__ float b2f(unsigned short u) {
  union { unsigned int u32; float f; } v; v.u32 = ((unsigned int)u) << 16; return v.f;
}
__device__ __forceinline__ unsigned short f2b(float f) {
  __bf16 h = (__bf16)f;
  return __builtin_bit_cast(unsigned short, h);
}

// A/B fragment load from LDS stored [rows][E] bf16, XOR-swizzled (byte ^= (row&7)<<4)
__device__ __forceinline__ bf16x8 ldfrag(const unsigned short* buf, int E, int r0, int k0, int lane) {
  int row = r0 + (lane & 15);
  int kb = (k0 + ((lane >> 4) << 3)) << 1;
  return *(const bf16x8*)(buf + row * E + ((kb ^ ((row & 7) << 4)) >> 1));
}
// Variant with explicit swizzle mask (for short rows, e.g. V^T with 64B rows)
__device__ __forceinline__ bf16x8 ldfragm(const unsigned short* buf, int E, int r0, int k0,
                                          int lane, int mask) {
  int row = r0 + (lane & 15);
  int kb = (k0 + ((lane >> 4) << 3)) << 1;
  return *(const bf16x8*)(buf + row * E + ((kb ^ ((row & mask) << 4)) >> 1));
}

__device__ __forceinline__ float4v mfma16(bf16x8 a, bf16x8 b, float4v c) {
  return __builtin_amdgcn_mfma_f32_16x16x32_bf16(a, b, c, 0, 0, 0);
}

// Convert fp32 weight W[K][N] (row-major) into fragment-ordered bf16 tiles
__global__ void prep_weights(const float* __restrict__ src, unsigned short* __restrict__ dst,
                             int K, int N) {
  int KT = K >> 5;
  int total = (N >> 4) * KT * 64;
  int t = blockIdx.x * blockDim.x + threadIdx.x;
  if (t >= total) return;
  int l = t & 63;
  int kt = (t >> 6) % KT;
  int nt = (t >> 6) / KT;
  int kbase = kt * 32 + ((l >> 4) << 3);
  int col = nt * 16 + (l & 15);
  ushort8v o;
  #pragma unroll
  for (int j = 0; j < 8; ++j) o[j] = f2b(src[(size_t)(kbase + j) * N + col]);
  *(ushort8v*)(dst + (size_t)t * 8) = o;
}

__global__ void zero_meta(int* meta) { if (threadIdx.x < 2) meta[threadIdx.x] = 0; }

// Bucket items by mt class. Output order is atomic (non-stable) but each item is
// processed identically by the main kernel -> output deterministic.
__global__ void bucket(const int* __restrict__ lengths, int* __restrict__ lists,
                       int* __restrict__ meta) {
  int i = blockIdx.x * blockDim.x + threadIdx.x;
  if (i >= 4096) return;
  int mt = (lengths[i] + 16) >> 4;
  if (mt <= 2) { int p = atomicAdd(&meta[0], 1); lists[p] = i; }
  else         { int p = atomicAdd(&meta[1], 1); lists[4096 + p] = i; }
}

// Wave computes MT m-tiles x NT n-tiles.  SLOTS=2: two in-place B prefetch
// slots (consume-then-refill, no copies). APRE=1 also double-slots A (LDS).
template<int NT, int KS, int MT, int SLOTS, int APRE>
__device__ __forceinline__ void mmN(const unsigned short* Ab, int EA,
                                    const bf16x8* __restrict__ Wf, int wnb, int KT, int l,
                                    float4v* acc) {
  if constexpr (SLOTS == 2) {
    bf16x8 p0[NT], p1[NT];
    #pragma unroll
    for (int n = 0; n < NT; ++n) {
      p0[n] = Wf[(size_t)((wnb + n) * KT) * 64 + l];
      p1[n] = Wf[(size_t)((wnb + n) * KT + 1) * 64 + l];
    }
    bf16x8 a0[MT], a1[MT];
    if constexpr (APRE) {
      #pragma unroll
      for (int m = 0; m < MT; ++m) {
        a0[m] = ldfrag(Ab, EA, m * 16, 0, l);
        a1[m] = ldfrag(Ab, EA, m * 16, 32, l);
      }
    }
    #pragma unroll 1
    for (int kt = 0; kt < KS; kt += 2) {
      {
        if constexpr (!APRE) {
          #pragma unroll
          for (int m = 0; m < MT; ++m) a0[m] = ldfrag(Ab, EA, m * 16, kt * 32, l);
        }
        #pragma unroll
        for (int n = 0; n < NT; ++n) {
          #pragma unroll
          for (int m = 0; m < MT; ++m)
            acc[m * NT + n] = mfma16(a0[m], p0[n], acc[m * NT + n]);
        }
        if (kt + 2 < KS) {
          #pragma unroll
          for (int n = 0; n < NT; ++n)
            p0[n] = Wf[(size_t)((wnb + n) * KT + kt + 2) * 64 + l];
          if constexpr (APRE) {
            #pragma unroll
            for (int m = 0; m < MT; ++m) a0[m] = ldfrag(Ab, EA, m * 16, (kt + 2) * 32, l);
          }
        }
      }
      {
        if constexpr (!APRE) {
          #pragma unroll
          for (int m = 0; m < MT; ++m) a1[m] = ldfrag(Ab, EA, m * 16, (kt + 1) * 32, l);
        }
        #pragma unroll
        for (int n = 0; n < NT; ++n) {
          #pragma unroll
          for (int m = 0; m < MT; ++m)
            acc[m * NT + n] = mfma16(a1[m], p1[n], acc[m * NT + n]);
        }
        if (kt + 3 < KS) {
          #pragma unroll
          for (int n = 0; n < NT; ++n)
            p1[n] = Wf[(size_t)((wnb + n) * KT + kt + 3) * 64 + l];
          if constexpr (APRE) {
            #pragma unroll
            for (int m = 0; m < MT; ++m) a1[m] = ldfrag(Ab, EA, m * 16, (kt + 3) * 32, l);
          }
        }
      }
    }
  } else {
    bf16x8 bn[NT];
    #pragma unroll
    for (int n = 0; n < NT; ++n) bn[n] = Wf[(size_t)((wnb + n) * KT) * 64 + l];
    #pragma unroll 1
    for (int kt = 0; kt < KS; ++kt) {
      bf16x8 a[MT];
      #pragma unroll
      for (int m = 0; m < MT; ++m) a[m] = ldfrag(Ab, EA, m * 16, kt * 32, l);
      #pragma unroll
      for (int n = 0; n < NT; ++n) {
        #pragma unroll
        for (int m = 0; m < MT; ++m)
          acc[m * NT + n] = mfma16(a[m], bn[n], acc[m * NT + n]);
      }
      if (kt + 1 < KS) {
        #pragma unroll
        for (int n = 0; n < NT; ++n)
          bn[n] = Wf[(size_t)((wnb + n) * KT + kt + 1) * 64 + l];
      }
    }
  }
}

// LayerNorm over rows {widx, widx+STRIDE, ...} < nrows of sXbuf [rows][512] bf16.
template<int STRIDE>
__device__ __forceinline__ void ln_pass(unsigned short* sXbuf, const float* __restrict__ g,
                                        const float* __restrict__ bb, int widx, int l, int nrows) {
  float gv[8], bv[8];
  {
    const float4* g4 = (const float4*)(g + l * 8);
    const float4* b4 = (const float4*)(bb + l * 8);
    float4 a0 = g4[0], a1 = g4[1], c0 = b4[0], c1 = b4[1];
    gv[0] = a0.x; gv[1] = a0.y; gv[2] = a0.z; gv[3] = a0.w;
    gv[4] = a1.x; gv[5] = a1.y; gv[6] = a1.z; gv[7] = a1.w;
    bv[0] = c0.x; bv[1] = c0.y; bv[2] = c0.z; bv[3] = c0.w;
    bv[4] = c1.x; bv[5] = c1.y; bv[6] = c1.z; bv[7] = c1.w;
  }
  #pragma unroll 1
  for (int r = widx; r < nrows; r += STRIDE) {
    int e = r * 512 + (((l << 4) ^ ((r & 7) << 4)) >> 1);  // cols l*8..l*8+7
    ushort8v x = *(const ushort8v*)(sXbuf + e);
    float v[8];
    float s = 0.f, s2 = 0.f;
    #pragma unroll
    for (int j = 0; j < 8; ++j) { v[j] = b2f(x[j]); s += v[j]; s2 += v[j] * v[j]; }
    #pragma unroll
    for (int off = 1; off < 64; off <<= 1) { s += __shfl_xor(s, off); s2 += __shfl_xor(s2, off); }
    float mu = s * (1.f / 512.f);
    float var = s2 * (1.f / 512.f) - mu * mu;
    float rstd = rsqrtf(var + 1e-6f);
    ushort8v o;
    #pragma unroll
    for (int j = 0; j < 8; ++j) o[j] = f2b((v[j] - mu) * rstd * gv[j] + bv[j]);
    *(ushort8v*)(sXbuf + e) = o;
  }
}

// Fused QKV sub-pass for the paired-small body: one n-tile triplet, MT=2,
// single-slot consume-then-refill. Writes Q (scaled), K; returns V acc.
__device__ __forceinline__ void qkv_pass(const unsigned short* sX,
                                         const unsigned short* wqkvf, int nt, int l,
                                         unsigned short* sQ, unsigned short* sK,
                                         const float* __restrict__ bqkv, float4v accV[2]) {
  const bf16x8* Wf = (const bf16x8*)wqkvf;
  float4v accQ[2], accK[2];
  accQ[0] = (float4v){0.f,0.f,0.f,0.f}; accQ[1] = accQ[0];
  accK[0] = accQ[0]; accK[1] = accQ[0];
  accV[0] = accQ[0]; accV[1] = accQ[0];
  const size_t bQ = (size_t)(nt) * 16 * 64 + l;        // KT=16
  const size_t bK = (size_t)(16 + nt) * 16 * 64 + l;
  const size_t bV = (size_t)(32 + nt) * 16 * 64 + l;
  bf16x8 q0 = Wf[bQ], k0 = Wf[bK], v0 = Wf[bV];
  #pragma unroll 1
  for (int kt = 0; kt < 16; ++kt) {
    bf16x8 a0 = ldfrag(sX, 512, 0, kt * 32, l);
    bf16x8 a1 = ldfrag(sX, 512, 16, kt * 32, l);
    accQ[0] = mfma16(a0, q0, accQ[0]); accQ[1] = mfma16(a1, q0, accQ[1]);
    accK[0] = mfma16(a0, k0, accK[0]); accK[1] = mfma16(a1, k0, accK[1]);
    accV[0] = mfma16(a0, v0, accV[0]); accV[1] = mfma16(a1, v0, accV[1]);
    if (kt + 1 < 16) {
      q0 = Wf[bQ + (size_t)(kt + 1) * 64];
      k0 = Wf[bK + (size_t)(kt + 1) * 64];
      v0 = Wf[bV + (size_t)(kt + 1) * 64];
    }
  }
  const float qscale = 0.044194173824159216f;  // 1/sqrt(512)
  int col = nt * 16 + (l & 15);
  float biasQ = bqkv[col];
  float biasK = bqkv[256 + col];
  #pragma unroll
  for (int m = 0; m < 2; ++m) {
    int r0 = m * 16 + ((l >> 4) << 2);
    #pragma unroll
    for (int j = 0; j < 4; ++j) {
      int r = r0 + j;
      sQ[r * 256 + (((col << 1) ^ ((r & 7) << 4)) >> 1)] = f2b((accQ[m][j] + biasQ) * qscale);
      sK[r * 256 + (((col << 1) ^ ((r & 7) << 4)) >> 1)] = f2b(accK[m][j] + biasK);
    }
  }
}

// Paired-small body: one item per 8-wave group (ws 0..7, ht 0..511), MT=2
// padded (mt=1 items just have more zero rows). 76KB LDS half.
// FF1 merged to one NT=2 pass; FF2/Wo kept as two NT=2 SLOTS=2 passes (the
// NT=4 single-slot variant regressed: no prefetch + spill).
__device__ __forceinline__ void small_body(
    unsigned short* sX, unsigned short* sQ, unsigned short* sK,
    float* sS, unsigned short* sP,
    const float* __restrict__ embed, const int* __restrict__ gidx,
    const float* __restrict__ b1, const float* __restrict__ b2,
    const float* __restrict__ ln1g, const float* __restrict__ ln1b,
    const float* __restrict__ bqkv, const float* __restrict__ bo,
    const float* __restrict__ ln2g, const float* __restrict__ ln2b,
    const unsigned short* __restrict__ w1f, const unsigned short* __restrict__ w2f,
    const unsigned short* __restrict__ wqkvf, const unsigned short* __restrict__ wof,
    float* __restrict__ out, int ht, int ws, int l, int item, int len) {

  // ---- phase 0: gather rows 0..31 (zeros beyond len) ----
  {
    int sub = ht >> 7;           // 0..3
    int c0 = (ht & 127) << 2;
    #pragma unroll 2
    for (int it = 0; it < 8; ++it) {
      int r = it * 4 + sub;
      float4 v = make_float4(0.f, 0.f, 0.f, 0.f);
      if (r <= len) {
        int row = gidx[item * K_S + r];
        v = *(const float4*)(embed + (size_t)row * K_D + c0);
      }
      ushort4v o;
      o[0] = f2b(v.x); o[1] = f2b(v.y); o[2] = f2b(v.z); o[3] = f2b(v.w);
      *(ushort4v*)(sX + r * 512 + (((c0 << 1) ^ ((r & 7) << 4)) >> 1)) = o;
    }
  }
  __syncthreads();

  // ---- phase 1: FF1, one NT=2 pass (2 n-tiles per wave) ----
  {
    float4v acc[4];
    #pragma unroll
    for (int i = 0; i < 4; ++i) acc[i] = (float4v){0.f,0.f,0.f,0.f};
    mmN<2, 16, 2, 2, 1>(sX, 512, (const bf16x8*)w1f, ws * 2, 16, l, acc);
    #pragma unroll
    for (int n = 0; n < 2; ++n) {
      int col = (ws * 2 + n) * 16 + (l & 15);
      float bias = b1[col];
      #pragma unroll
      for (int m = 0; m < 2; ++m) {
        int r0 = m * 16 + ((l >> 4) << 2);
        #pragma unroll
        for (int j = 0; j < 4; ++j) {
          int r = r0 + j;
          sQ[r * 256 + (((col << 1) ^ ((r & 7) << 4)) >> 1)] = f2b(fmaxf(acc[m * 2 + n][j] + bias, 0.f));
        }
      }
    }
  }
  __syncthreads();

  // ---- phase 2: FF2 (two NT=2 SLOTS=2 passes) + residual ----
  #pragma unroll 1
  for (int p = 0; p < 2; ++p) {
    float4v acc[4];
    #pragma unroll
    for (int i = 0; i < 4; ++i) acc[i] = (float4v){0.f,0.f,0.f,0.f};
    mmN<2, 8, 2, 2, 1>(sQ, 256, (const bf16x8*)w2f, ws * 4 + p * 2, 8, l, acc);
    #pragma unroll
    for (int n = 0; n < 2; ++n) {
      int col = (ws * 4 + p * 2 + n) * 16 + (l & 15);
      float bias = b2[col];
      #pragma unroll
      for (int m = 0; m < 2; ++m) {
        int r0 = m * 16 + ((l >> 4) << 2);
        #pragma unroll
        for (int j = 0; j < 4; ++j) {
          int r = r0 + j;
          int e = r * 512 + (((col << 1) ^ ((r & 7) << 4)) >> 1);
          sX[e] = f2b(acc[m * 2 + n][j] + bias + b2f(sX[e]));
        }
      }
    }
  }
  __syncthreads();
  ln_pass<8>(sX, ln1g, ln1b, ws, l, 32);
  __syncthreads();

  // ---- phase 3: fused QKV (two triplet sub-passes); V kept in regs ----
  float4v accV0[2], accV1[2];
  qkv_pass(sX, wqkvf, ws * 2 + 0, l, sQ, sK, bqkv, accV0);
  qkv_pass(sX, wqkvf, ws * 2 + 1, l, sQ, sK, bqkv, accV1);
  __syncthreads();

  // ---- phase 4: scores (waves 0..3), tile (ws>>1, ws&1) ----
  if (ws < 4) {
    int m0 = (ws >> 1) * 16, n0 = (ws & 1) * 16;
    float4v acc = (float4v){0.f,0.f,0.f,0.f};
    bf16x8 b0 = ldfrag(sK, 256, n0, 0, l),  aq0 = ldfrag(sQ, 256, m0, 0, l);
    bf16x8 b1 = ldfrag(sK, 256, n0, 32, l), aq1 = ldfrag(sQ, 256, m0, 32, l);
    #pragma unroll 1
    for (int kt = 0; kt < 8; kt += 2) {
      acc = mfma16(aq0, b0, acc);
      if (kt + 2 < 8) { b0 = ldfrag(sK, 256, n0, (kt + 2) * 32, l); aq0 = ldfrag(sQ, 256, m0, (kt + 2) * 32, l); }
      acc = mfma16(aq1, b1, acc);
      if (kt + 3 < 8) { b1 = ldfrag(sK, 256, n0, (kt + 3) * 32, l); aq1 = ldfrag(sQ, 256, m0, (kt + 3) * 32, l); }
    }
    int col = n0 + (l & 15);
    int r0 = m0 + ((l >> 4) << 2);
    #pragma unroll
    for (int j = 0; j < 4; ++j) {
      int r = r0 + j;
      sS[r * 64 + (((col << 2) ^ ((r & 7) << 4)) >> 2)] = acc[j];
    }
  }
  __syncthreads();

  // ---- phase 5: softmax (4 rows/wave) -> sP; V^T -> sK (KVP=32, SWM=3) ----
  {
    const bool valid = (l <= len);
    #pragma unroll 1
    for (int r = ws; r < 32; r += 8) {
      float s = valid ? sS[r * 64 + (((l << 2) ^ ((r & 7) << 4)) >> 2)] : -1e30f;
      float mx = s;
      #pragma unroll
      for (int off = 1; off < 64; off <<= 1) mx = fmaxf(mx, __shfl_xor(mx, off));
      float p = valid ? __expf(s - mx) : 0.f;
      float sum = p;
      #pragma unroll
      for (int off = 1; off < 64; off <<= 1) sum += __shfl_xor(sum, off);
      sP[r * 64 + (((l << 1) ^ ((r & 7) << 4)) >> 1)] = f2b(p / sum);
    }
    #pragma unroll
    for (int p = 0; p < 2; ++p) {
      int c = (ws * 2 + p) * 16 + (l & 15);
      float biasV = bqkv[512 + c];
      const float4v* aV = p ? accV1 : accV0;
      #pragma unroll
      for (int m = 0; m < 2; ++m) {
        int r0 = m * 16 + ((l >> 4) << 2);
        ushort4v o;
        #pragma unroll
        for (int j = 0; j < 4; ++j) o[j] = f2b(aV[m][j] + biasV);
        *(ushort4v*)(sK + c * 32 + (((r0 << 1) ^ ((c & 3) << 4)) >> 1)) = o;
      }
    }
  }
  __syncthreads();

  // ---- phase 7: ctx = P @ V (2 n-tiles, merged: P loaded once) -> sQ ----
  {
    bf16x8 pa0 = ldfrag(sP, 64, 0, 0, l);
    bf16x8 pa1 = ldfrag(sP, 64, 16, 0, l);
    bf16x8 bf0 = ldfragm(sK, 32, (ws * 2 + 0) * 16, 0, l, 3);
    bf16x8 bf1 = ldfragm(sK, 32, (ws * 2 + 1) * 16, 0, l, 3);
    float4v z = (float4v){0.f,0.f,0.f,0.f};
    float4v c00 = mfma16(pa0, bf0, z), c10 = mfma16(pa1, bf0, z);
    float4v c01 = mfma16(pa0, bf1, z), c11 = mfma16(pa1, bf1, z);
    #pragma unroll
    for (int p = 0; p < 2; ++p) {
      int col = (ws * 2 + p) * 16 + (l & 15);
      #pragma unroll
      for (int m = 0; m < 2; ++m) {
        const float4v& cc = p ? (m ? c11 : c01) : (m ? c10 : c00);
        int r0 = m * 16 + ((l >> 4) << 2);
        #pragma unroll
        for (int j = 0; j < 4; ++j) {
          int r = r0 + j;
          sQ[r * 256 + (((col << 1) ^ ((r & 7) << 4)) >> 1)] = f2b(cc[j]);
        }
      }
    }
  }
  __syncthreads();

  // ---- phase 8: Wo (two NT=2 SLOTS=2 passes) + residual ----
  #pragma unroll 1
  for (int p = 0; p < 2; ++p) {
    float4v acc[4];
    #pragma unroll
    for (int i = 0; i < 4; ++i) acc[i] = (float4v){0.f,0.f,0.f,0.f};
    mmN<2, 8, 2, 2, 1>(sQ, 256, (const bf16x8*)wof, ws * 4 + p * 2, 8, l, acc);
    #pragma unroll
    for (int n = 0; n < 2; ++n) {
      int col = (ws * 4 + p * 2 + n) * 16 + (l & 15);
      float bias = bo[col];
      #pragma unroll
      for (int m = 0; m < 2; ++m) {
        int r0 = m * 16 + ((l >> 4) << 2);
        #pragma unroll
        for (int j = 0; j < 4; ++j) {
          int r = r0 + j;
          int e = r * 512 + (((col << 1) ^ ((r & 7) << 4)) >> 1);
          sX[e] = f2b(acc[m * 2 + n][j] + bias + b2f(sX[e]));
        }
      }
    }
  }
  __syncthreads();
  ln_pass<8>(sX, ln2g, ln2b, ws, l, 32);
  __syncthreads();

  // ---- phase 9: masked mean pool (one col per thread, serial rows) ----
  {
    float sum = 0.f;
    for (int s = 0; s <= len; ++s)
      sum += b2f(sX[s * 512 + (((ht << 1) ^ ((s & 7) << 4)) >> 1)]);
    out[(size_t)item * K_D + ht] = sum / (float)(len + 1);
  }
}

// R11-structure big body (MT=3/4), full 152KB layout.
template<int MT>
__device__ __forceinline__ void big_body(
    unsigned short* sX, unsigned short* sQ, unsigned short* sK,
    float* sS, unsigned short* sP,
    const float* __restrict__ embed, const int* __restrict__ gidx,
    const float* __restrict__ b1, const float* __restrict__ b2,
    const float* __restrict__ ln1g, const float* __restrict__ ln1b,
    const float* __restrict__ bqkv, const float* __restrict__ bo,
    const float* __restrict__ ln2g, const float* __restrict__ ln2b,
    const unsigned short* __restrict__ w1f, const unsigned short* __restrict__ w2f,
    const unsigned short* __restrict__ wqkvf, const unsigned short* __restrict__ wof,
    float* __restrict__ out, int tid, int w, int l, int item, int len) {

  constexpr int ROWS = 16 * MT;
  constexpr int S2 = (MT <= 3) ? 2 : 1;
  constexpr int AP1 = (MT <= 3) ? 1 : 0;

  {
    const int sub = tid >> 7;
    const int c0 = (tid & 127) << 2;
    #pragma unroll 2
    for (int it = 0; it < 2 * MT; ++it) {
      int r = it * 8 + sub;
      float4 v = make_float4(0.f, 0.f, 0.f, 0.f);
      if (r <= len) {
        int row = gidx[item * K_S + r];
        v = *(const float4*)(embed + (size_t)row * K_D + c0);
      }
      ushort4v o;
      o[0] = f2b(v.x); o[1] = f2b(v.y); o[2] = f2b(v.z); o[3] = f2b(v.w);
      *(ushort4v*)(sX + r * 512 + (((c0 << 1) ^ ((r & 7) << 4)) >> 1)) = o;
    }
  }
  __syncthreads();

  {
    float4v acc[MT];
    #pragma unroll
    for (int i = 0; i < MT; ++i) acc[i] = (float4v){0.f,0.f,0.f,0.f};
    mmN<1, 16, MT, 2, AP1>(sX, 512, (const bf16x8*)w1f, w, 16, l, acc);
    int col = w * 16 + (l & 15);
    float bias = b1[col];
    #pragma unroll
    for (int m = 0; m < MT; ++m) {
      int r0 = m * 16 + ((l >> 4) << 2);
      #pragma unroll
      for (int j = 0; j < 4; ++j) {
        int r = r0 + j;
        sQ[r * 256 + (((col << 1) ^ ((r & 7) << 4)) >> 1)] = f2b(fmaxf(acc[m][j] + bias, 0.f));
      }
    }
  }
  __syncthreads();

  {
    float4v acc[2 * MT];
    #pragma unroll
    for (int i = 0; i < 2 * MT; ++i) acc[i] = (float4v){0.f,0.f,0.f,0.f};
    mmN<2, 8, MT, S2, 0>(sQ, 256, (const bf16x8*)w2f, w * 2, 8, l, acc);
    #pragma unroll
    for (int n = 0; n < 2; ++n) {
      int col = (w * 2 + n) * 16 + (l & 15);
      float bias = b2[col];
      #pragma unroll
      for (int m = 0; m < MT; ++m) {
        int r0 = m * 16 + ((l >> 4) << 2);
        #pragma unroll
        for (int j = 0; j < 4; ++j) {
          int r = r0 + j;
          int e = r * 512 + (((col << 1) ^ ((r & 7) << 4)) >> 1);
          sX[e] = f2b(acc[m * 2 + n][j] + bias + b2f(sX[e]));
        }
      }
    }
  }
  __syncthreads();
  ln_pass<16>(sX, ln1g, ln1b, w, l, ROWS);
  __syncthreads();

  {
    const bf16x8* Wf = (const bf16x8*)wqkvf;
    float4v accQ[MT], accK[MT];
    #pragma unroll
    for (int i = 0; i < MT; ++i) {
      accQ[i] = (float4v){0.f,0.f,0.f,0.f};
      accK[i] = (float4v){0.f,0.f,0.f,0.f};
    }
    const size_t baseQ = (size_t)(w) * 16 * 64 + l;
    const size_t baseK = (size_t)(16 + w) * 16 * 64 + l;
    bf16x8 q0 = Wf[baseQ], k0 = Wf[baseK];
    #pragma unroll 1
    for (int kt = 0; kt < 16; ++kt) {
      bf16x8 a[MT];
      #pragma unroll
      for (int m = 0; m < MT; ++m) a[m] = ldfrag(sX, 512, m * 16, kt * 32, l);
      #pragma unroll
      for (int m = 0; m < MT; ++m) accQ[m] = mfma16(a[m], q0, accQ[m]);
      #pragma unroll
      for (int m = 0; m < MT; ++m) accK[m] = mfma16(a[m], k0, accK[m]);
      if (kt + 1 < 16) {
        q0 = Wf[baseQ + (size_t)(kt + 1) * 64];
        k0 = Wf[baseK + (size_t)(kt + 1) * 64];
      }
    }
    const float qscale = 0.044194173824159216f;
    int col = w * 16 + (l & 15);
    float biasQ = bqkv[col];
    float biasK = bqkv[256 + col];
    #pragma unroll
    for (int m = 0; m < MT; ++m) {
      int r0 = m * 16 + ((l >> 4) << 2);
      #pragma unroll
      for (int j = 0; j < 4; ++j) {
        int r = r0 + j;
        sQ[r * 256 + (((col << 1) ^ ((r & 7) << 4)) >> 1)] = f2b((accQ[m][j] + biasQ) * qscale);
        sK[r * 256 + (((col << 1) ^ ((r & 7) << 4)) >> 1)] = f2b(accK[m][j] + biasK);
      }
    }
  }
  __syncthreads();

  if ((w >> 2) < MT) {
    float4v acc = (float4v){0.f,0.f,0.f,0.f};
    int n0 = (w & 3) * 16;
    int m0 = (w >> 2) * 16;
    bf16x8 b0 = ldfrag(sK, 256, n0, 0, l),  aq0 = ldfrag(sQ, 256, m0, 0, l);
    bf16x8 b1 = ldfrag(sK, 256, n0, 32, l), aq1 = ldfrag(sQ, 256, m0, 32, l);
    #pragma unroll 1
    for (int kt = 0; kt < 8; kt += 2) {
      acc = mfma16(aq0, b0, acc);
      if (kt + 2 < 8) { b0 = ldfrag(sK, 256, n0, (kt + 2) * 32, l); aq0 = ldfrag(sQ, 256, m0, (kt + 2) * 32, l); }
      acc = mfma16(aq1, b1, acc);
      if (kt + 3 < 8) { b1 = ldfrag(sK, 256, n0, (kt + 3) * 32, l); aq1 = ldfrag(sQ, 256, m0, (kt + 3) * 32, l); }
    }
    int col = n0 + (l & 15);
    int r0 = m0 + ((l >> 4) << 2);
    #pragma unroll
    for (int j = 0; j < 4; ++j) {
      int r = r0 + j;
      sS[r * 64 + (((col << 2) ^ ((r & 7) << 4)) >> 2)] = acc[j];
    }
  }
  float4v accV[MT];
  {
    #pragma unroll
    for (int i = 0; i < MT; ++i) accV[i] = (float4v){0.f,0.f,0.f,0.f};
    mmN<1, 16, MT, 2, AP1>(sX, 512, (const bf16x8*)wqkvf, 32 + w, 16, l, accV);
  }
  __syncthreads();

  {
    const bool valid = (l <= len);
    #pragma unroll 1
    for (int r = w; r < ROWS; r += 16) {
      float s = valid ? sS[r * 64 + (((l << 2) ^ ((r & 7) << 4)) >> 2)] : -1e30f;
      float mx = s;
      #pragma unroll
      for (int off = 1; off < 64; off <<= 1) mx = fmaxf(mx, __shfl_xor(mx, off));
      float p = valid ? __expf(s - mx) : 0.f;
      float sum = p;
      #pragma unroll
      for (int off = 1; off < 64; off <<= 1) sum += __shfl_xor(sum, off);
      sP[r * 64 + (((l << 1) ^ ((r & 7) << 4)) >> 1)] = f2b(p / sum);
    }
    int c = w * 16 + (l & 15);
    float biasV = bqkv[512 + c];
    #pragma unroll
    for (int m = 0; m < MT; ++m) {
      int r0 = m * 16 + ((l >> 4) << 2);
      ushort4v o;
      #pragma unroll
      for (int j = 0; j < 4; ++j) o[j] = f2b(accV[m][j] + biasV);
      *(ushort4v*)(sK + c * 64 + (((r0 << 1) ^ ((c & 7) << 4)) >> 1)) = o;
    }
    #pragma unroll
    for (int m = MT; m < 4; ++m) {
      int r0 = m * 16 + ((l >> 4) << 2);
      ushort4v o; o[0] = 0; o[1] = 0; o[2] = 0; o[3] = 0;
      *(ushort4v*)(sK + c * 64 + (((r0 << 1) ^ ((c & 7) << 4)) >> 1)) = o;
    }
  }
  __syncthreads();

  {
    float4v acc[MT];
    #pragma unroll
    for (int i = 0; i < MT; ++i) acc[i] = (float4v){0.f,0.f,0.f,0.f};
    #pragma unroll
    for (int kt = 0; kt < 2; ++kt) {
      bf16x8 bfr = ldfragm(sK, 64, w * 16, kt * 32, l, 7);
      #pragma unroll
      for (int m = 0; m < MT; ++m) {
        bf16x8 a = ldfrag(sP, 64, m * 16, kt * 32, l);
        acc[m] = mfma16(a, bfr, acc[m]);
      }
    }
    int col = w * 16 + (l & 15);
    #pragma unroll
    for (int m = 0; m < MT; ++m) {
      int r0 = m * 16 + ((l >> 4) << 2);
      #pragma unroll
      for (int j = 0; j < 4; ++j) {
        int r = r0 + j;
        sQ[r * 256 + (((col << 1) ^ ((r & 7) << 4)) >> 1)] = f2b(acc[m][j]);
      }
    }
  }
  __syncthreads();

  {
    float4v acc[2 * MT];
    #pragma unroll
    for (int i = 0; i < 2 * MT; ++i) acc[i] = (float4v){0.f,0.f,0.f,0.f};
    mmN<2, 8, MT, S2, 0>(sQ, 256, (const bf16x8*)wof, w * 2, 8, l, acc);
    #pragma unroll
    for (int n = 0; n < 2; ++n) {
      int col = (w * 2 + n) * 16 + (l & 15);
      float bias = bo[col];
      #pragma unroll
      for (int m = 0; m < MT; ++m) {
        int r0 = m * 16 + ((l >> 4) << 2);
        #pragma unroll
        for (int j = 0; j < 4; ++j) {
          int r = r0 + j;
          int e = r * 512 + (((col << 1) ^ ((r & 7) << 4)) >> 1);
          sX[e] = f2b(acc[m * 2 + n][j] + bias + b2f(sX[e]));
        }
      }
    }
  }
  __syncthreads();
  ln_pass<16>(sX, ln2g, ln2b, w, l, ROWS);
  __syncthreads();

  {
    int col = tid & 511;
    int half = tid >> 9;
    float sum = 0.f;
    for (int s = half; s <= len; s += 2)
      sum += b2f(sX[s * 512 + (((col << 1) ^ ((s & 7) << 4)) >> 1)]);
    if (half) sS[col] = sum;
    __syncthreads();
    if (!half) out[(size_t)item * K_D + col] = (sum + sS[col]) / (float)(len + 1);
  }
}

__global__ __launch_bounds__(1024, 4)
void fused_all(
    const float* __restrict__ embed, const int* __restrict__ gidx,
    const int* __restrict__ lengths,
    const float* __restrict__ b1, const float* __restrict__ b2,
    const float* __restrict__ ln1g, const float* __restrict__ ln1b,
    const float* __restrict__ bqkv, const float* __restrict__ bo,
    const float* __restrict__ ln2g, const float* __restrict__ ln2b,
    const unsigned short* __restrict__ w1f, const unsigned short* __restrict__ w2f,
    const unsigned short* __restrict__ wqkvf, const unsigned short* __restrict__ wof,
    const int* __restrict__ lists, const int* __restrict__ meta,
    float* __restrict__ out) {
  __shared__ unsigned char lds[155648];

  const int tid = (int)threadIdx.x;
  const int w = tid >> 6;
  const int l = tid & 63;
  const int j = (int)blockIdx.x;
  const int nsmall = meta[0];
  const int nbig = meta[1];

  if (j < 2048) {
    // paired-small region: items lists[2j], lists[2j+1]
    if (2 * j >= nsmall) return;
    int i0 = lists[2 * j];
    int i1 = (2 * j + 1 < nsmall) ? lists[2 * j + 1] : i0;  // dup: benign re-write
    int h = w >> 3;
    int ws = w & 7;
    int ht = ws * 64 + l;
    int item = h ? i1 : i0;
    int len = lengths[item];
    size_t base = (size_t)h * 77824;
    unsigned short* sX = (unsigned short*)(lds + base);
    unsigned short* sQ = (unsigned short*)(lds + base + 32768);
    unsigned short* sK = (unsigned short*)(lds + base + 49152);
    float* sS = (float*)(lds + base + 65536);
    unsigned short* sP = (unsigned short*)(lds + base + 73728);
    small_body(sX, sQ, sK, sS, sP, embed, gidx, b1, b2, ln1g, ln1b, bqkv, bo,
               ln2g, ln2b, w1f, w2f, wqkvf, wof, out, ht, ws, l, item, len);
  } else {
    int bi = j - 2048;
    if (bi >= nbig) return;
    int item = lists[4096 + bi];
    int len = lengths[item];
    int mt = (len + 16) >> 4;
    unsigned short* sX = (unsigned short*)lds;
    unsigned short* sQ = (unsigned short*)(lds + 65536);
    unsigned short* sK = (unsigned short*)(lds + 98304);
    float* sS = (float*)(lds + 131072);
    unsigned short* sP = (unsigned short*)(lds + 147456);
    if (mt == 3)
      big_body<3>(sX, sQ, sK, sS, sP, embed, gidx, b1, b2, ln1g, ln1b, bqkv, bo,
                  ln2g, ln2b, w1f, w2f, wqkvf, wof, out, tid, w, l, item, len);
    else
      big_body<4>(sX, sQ, sK, sS, sP, embed, gidx, b1, b2, ln1g, ln1b, bqkv, bo,
                  ln2g, ln2b, w1f, w2f, wqkvf, wof, out, tid, w, l, item, len);
  }
}

extern "C" void kernel_launch(void* const* d_in, const int* in_sizes, int n_in,
                              void* d_out, int out_size, void* d_ws, size_t ws_size,
                              hipStream_t stream) {
  (void)in_sizes; (void)n_in; (void)out_size; (void)ws_size;
  const float* embed = (const float*)d_in[0];
  const int* idx = (const int*)d_in[1];
  const int* lengths = (const int*)d_in[2];
  const float* W1 = (const float*)d_in[3];
  const float* b1 = (const float*)d_in[4];
  const float* W2 = (const float*)d_in[5];
  const float* b2 = (const float*)d_in[6];
  const float* ln1g = (const float*)d_in[7];
  const float* ln1b = (const float*)d_in[8];
  const float* Wqkv = (const float*)d_in[9];
  const float* bqkv = (const float*)d_in[10];
  const float* Wo = (const float*)d_in[11];
  const float* bo = (const float*)d_in[12];
  const float* ln2g = (const float*)d_in[13];
  const float* ln2b = (const float*)d_in[14];

  unsigned short* ws = (unsigned short*)d_ws;
  unsigned short* w1f = ws;                 // 131072 bf16
  unsigned short* w2f = ws + 131072;        // 131072
  unsigned short* wqkvf = ws + 262144;      // 393216
  unsigned short* wof = ws + 655360;        // 131072  -> ends at 786432
  int* lists = (int*)(ws + 786432);         // 8192 ints
  int* meta = lists + 8192;                 // 2 ints

  prep_weights<<<64, 256, 0, stream>>>(W1, w1f, 512, 256);
  prep_weights<<<64, 256, 0, stream>>>(W2, w2f, 256, 512);
  prep_weights<<<192, 256, 0, stream>>>(Wqkv, wqkvf, 512, 768);
  prep_weights<<<64, 256, 0, stream>>>(Wo, wof, 256, 512);
  zero_meta<<<1, 64, 0, stream>>>(meta);
  bucket<<<16, 256, 0, stream>>>(lengths, lists, meta);

  fused_all<<<6144, 1024, 0, stream>>>(embed, idx, lengths, b1, b2, ln1g, ln1b,
                                       bqkv, bo, ln2g, ln2b, w1f, w2f, wqkvf, wof,
                                       lists, meta, (float*)d_out);
}

// Round 18
// 481.868 us; speedup vs baseline: 1.1212x; 1.0368x over previous
//
#include <hip/hip_runtime.h>

typedef __bf16 bf16x8 __attribute__((ext_vector_type(8)));
typedef float float4v __attribute__((ext_vector_type(4)));
typedef unsigned short ushort4v __attribute__((ext_vector_type(4)));
typedef unsigned short ushort8v __attribute__((ext_vector_type(8)));

#define K_D 512
#define K_S 50

__device__ __forceinline__ float b2f(unsigned short u) {
  union { unsigned int u32; float f; } v; v.u32 = ((unsigned int)u) << 16; return v.f;
}
__device__ __forceinline__ unsigned short f2b(float f) {
  __bf16 h = (__bf16)f;
  return __builtin_bit_cast(unsigned short, h);
}

// A/B fragment load from LDS stored [rows][E] bf16, XOR-swizzled (byte ^= (row&7)<<4)
__device__ __forceinline__ bf16x8 ldfrag(const unsigned short* buf, int E, int r0, int k0, int lane) {
  int row = r0 + (lane & 15);
  int kb = (k0 + ((lane >> 4) << 3)) << 1;
  return *(const bf16x8*)(buf + row * E + ((kb ^ ((row & 7) << 4)) >> 1));
}
// Variant with explicit swizzle mask (for short rows, e.g. V^T with 64B rows)
__device__ __forceinline__ bf16x8 ldfragm(const unsigned short* buf, int E, int r0, int k0,
                                          int lane, int mask) {
  int row = r0 + (lane & 15);
  int kb = (k0 + ((lane >> 4) << 3)) << 1;
  return *(const bf16x8*)(buf + row * E + ((kb ^ ((row & mask) << 4)) >> 1));
}

__device__ __forceinline__ float4v mfma16(bf16x8 a, bf16x8 b, float4v c) {
  return __builtin_amdgcn_mfma_f32_16x16x32_bf16(a, b, c, 0, 0, 0);
}

// Convert fp32 weight W[K][N] (row-major) into fragment-ordered bf16 tiles
__global__ void prep_weights(const float* __restrict__ src, unsigned short* __restrict__ dst,
                             int K, int N) {
  int KT = K >> 5;
  int total = (N >> 4) * KT * 64;
  int t = blockIdx.x * blockDim.x + threadIdx.x;
  if (t >= total) return;
  int l = t & 63;
  int kt = (t >> 6) % KT;
  int nt = (t >> 6) / KT;
  int kbase = kt * 32 + ((l >> 4) << 3);
  int col = nt * 16 + (l & 15);
  ushort8v o;
  #pragma unroll
  for (int j = 0; j < 8; ++j) o[j] = f2b(src[(size_t)(kbase + j) * N + col]);
  *(ushort8v*)(dst + (size_t)t * 8) = o;
}

__global__ void zero_meta(int* meta) { if (threadIdx.x < 3) meta[threadIdx.x] = 0; }

// Bucket items into three mt classes. Atomic order is non-stable, but every
// item's output is computed identically regardless of position -> deterministic.
__global__ void bucket(const int* __restrict__ lengths, int* __restrict__ lists,
                       int* __restrict__ meta) {
  int i = blockIdx.x * blockDim.x + threadIdx.x;
  if (i >= 4096) return;
  int mt = (lengths[i] + 16) >> 4;
  if (mt == 1)      { int p = atomicAdd(&meta[0], 1); lists[p] = i; }
  else if (mt == 2) { int p = atomicAdd(&meta[1], 1); lists[4096 + p] = i; }
  else              { int p = atomicAdd(&meta[2], 1); lists[8192 + p] = i; }
}

// Wave computes MT m-tiles x NT n-tiles.  SLOTS=2: two in-place B prefetch
// slots (consume-then-refill, no copies). APRE=1 also double-slots A (LDS).
template<int NT, int KS, int MT, int SLOTS, int APRE>
__device__ __forceinline__ void mmN(const unsigned short* Ab, int EA,
                                    const bf16x8* __restrict__ Wf, int wnb, int KT, int l,
                                    float4v* acc) {
  if constexpr (SLOTS == 2) {
    bf16x8 p0[NT], p1[NT];
    #pragma unroll
    for (int n = 0; n < NT; ++n) {
      p0[n] = Wf[(size_t)((wnb + n) * KT) * 64 + l];
      p1[n] = Wf[(size_t)((wnb + n) * KT + 1) * 64 + l];
    }
    bf16x8 a0[MT], a1[MT];
    if constexpr (APRE) {
      #pragma unroll
      for (int m = 0; m < MT; ++m) {
        a0[m] = ldfrag(Ab, EA, m * 16, 0, l);
        a1[m] = ldfrag(Ab, EA, m * 16, 32, l);
      }
    }
    #pragma unroll 1
    for (int kt = 0; kt < KS; kt += 2) {
      {
        if constexpr (!APRE) {
          #pragma unroll
          for (int m = 0; m < MT; ++m) a0[m] = ldfrag(Ab, EA, m * 16, kt * 32, l);
        }
        #pragma unroll
        for (int n = 0; n < NT; ++n) {
          #pragma unroll
          for (int m = 0; m < MT; ++m)
            acc[m * NT + n] = mfma16(a0[m], p0[n], acc[m * NT + n]);
        }
        if (kt + 2 < KS) {
          #pragma unroll
          for (int n = 0; n < NT; ++n)
            p0[n] = Wf[(size_t)((wnb + n) * KT + kt + 2) * 64 + l];
          if constexpr (APRE) {
            #pragma unroll
            for (int m = 0; m < MT; ++m) a0[m] = ldfrag(Ab, EA, m * 16, (kt + 2) * 32, l);
          }
        }
      }
      {
        if constexpr (!APRE) {
          #pragma unroll
          for (int m = 0; m < MT; ++m) a1[m] = ldfrag(Ab, EA, m * 16, (kt + 1) * 32, l);
        }
        #pragma unroll
        for (int n = 0; n < NT; ++n) {
          #pragma unroll
          for (int m = 0; m < MT; ++m)
            acc[m * NT + n] = mfma16(a1[m], p1[n], acc[m * NT + n]);
        }
        if (kt + 3 < KS) {
          #pragma unroll
          for (int n = 0; n < NT; ++n)
            p1[n] = Wf[(size_t)((wnb + n) * KT + kt + 3) * 64 + l];
          if constexpr (APRE) {
            #pragma unroll
            for (int m = 0; m < MT; ++m) a1[m] = ldfrag(Ab, EA, m * 16, (kt + 3) * 32, l);
          }
        }
      }
    }
  } else {
    bf16x8 bn[NT];
    #pragma unroll
    for (int n = 0; n < NT; ++n) bn[n] = Wf[(size_t)((wnb + n) * KT) * 64 + l];
    #pragma unroll 1
    for (int kt = 0; kt < KS; ++kt) {
      bf16x8 a[MT];
      #pragma unroll
      for (int m = 0; m < MT; ++m) a[m] = ldfrag(Ab, EA, m * 16, kt * 32, l);
      #pragma unroll
      for (int n = 0; n < NT; ++n) {
        #pragma unroll
        for (int m = 0; m < MT; ++m)
          acc[m * NT + n] = mfma16(a[m], bn[n], acc[m * NT + n]);
      }
      if (kt + 1 < KS) {
        #pragma unroll
        for (int n = 0; n < NT; ++n)
          bn[n] = Wf[(size_t)((wnb + n) * KT + kt + 1) * 64 + l];
      }
    }
  }
}

// LayerNorm over rows {widx, widx+STRIDE, ...} < nrows of sXbuf [rows][512] bf16.
template<int STRIDE>
__device__ __forceinline__ void ln_pass(unsigned short* sXbuf, const float* __restrict__ g,
                                        const float* __restrict__ bb, int widx, int l, int nrows) {
  float gv[8], bv[8];
  {
    const float4* g4 = (const float4*)(g + l * 8);
    const float4* b4 = (const float4*)(bb + l * 8);
    float4 a0 = g4[0], a1 = g4[1], c0 = b4[0], c1 = b4[1];
    gv[0] = a0.x; gv[1] = a0.y; gv[2] = a0.z; gv[3] = a0.w;
    gv[4] = a1.x; gv[5] = a1.y; gv[6] = a1.z; gv[7] = a1.w;
    bv[0] = c0.x; bv[1] = c0.y; bv[2] = c0.z; bv[3] = c0.w;
    bv[4] = c1.x; bv[5] = c1.y; bv[6] = c1.z; bv[7] = c1.w;
  }
  #pragma unroll 1
  for (int r = widx; r < nrows; r += STRIDE) {
    int e = r * 512 + (((l << 4) ^ ((r & 7) << 4)) >> 1);  // cols l*8..l*8+7
    ushort8v x = *(const ushort8v*)(sXbuf + e);
    float v[8];
    float s = 0.f, s2 = 0.f;
    #pragma unroll
    for (int j = 0; j < 8; ++j) { v[j] = b2f(x[j]); s += v[j]; s2 += v[j] * v[j]; }
    #pragma unroll
    for (int off = 1; off < 64; off <<= 1) { s += __shfl_xor(s, off); s2 += __shfl_xor(s2, off); }
    float mu = s * (1.f / 512.f);
    float var = s2 * (1.f / 512.f) - mu * mu;
    float rstd = rsqrtf(var + 1e-6f);
    ushort8v o;
    #pragma unroll
    for (int j = 0; j < 8; ++j) o[j] = f2b((v[j] - mu) * rstd * gv[j] + bv[j]);
    *(ushort8v*)(sXbuf + e) = o;
  }
}

// Fused QKV sub-pass: one n-tile triplet, MT m-tiles, single-slot
// consume-then-refill. Writes Q (scaled), K; returns V acc.
template<int MT>
__device__ __forceinline__ void qkv_pass(const unsigned short* sX,
                                         const unsigned short* wqkvf, int nt, int l,
                                         unsigned short* sQ, unsigned short* sK,
                                         const float* __restrict__ bqkv, float4v accV[MT]) {
  const bf16x8* Wf = (const bf16x8*)wqkvf;
  float4v accQ[MT], accK[MT];
  #pragma unroll
  for (int m = 0; m < MT; ++m) {
    accQ[m] = (float4v){0.f,0.f,0.f,0.f};
    accK[m] = accQ[m];
    accV[m] = accQ[m];
  }
  const size_t bQ = (size_t)(nt) * 16 * 64 + l;        // KT=16
  const size_t bK = (size_t)(16 + nt) * 16 * 64 + l;
  const size_t bV = (size_t)(32 + nt) * 16 * 64 + l;
  bf16x8 q0 = Wf[bQ], k0 = Wf[bK], v0 = Wf[bV];
  #pragma unroll 1
  for (int kt = 0; kt < 16; ++kt) {
    bf16x8 a[MT];
    #pragma unroll
    for (int m = 0; m < MT; ++m) a[m] = ldfrag(sX, 512, m * 16, kt * 32, l);
    #pragma unroll
    for (int m = 0; m < MT; ++m) accQ[m] = mfma16(a[m], q0, accQ[m]);
    #pragma unroll
    for (int m = 0; m < MT; ++m) accK[m] = mfma16(a[m], k0, accK[m]);
    #pragma unroll
    for (int m = 0; m < MT; ++m) accV[m] = mfma16(a[m], v0, accV[m]);
    if (kt + 1 < 16) {
      q0 = Wf[bQ + (size_t)(kt + 1) * 64];
      k0 = Wf[bK + (size_t)(kt + 1) * 64];
      v0 = Wf[bV + (size_t)(kt + 1) * 64];
    }
  }
  const float qscale = 0.044194173824159216f;  // 1/sqrt(512)
  int col = nt * 16 + (l & 15);
  float biasQ = bqkv[col];
  float biasK = bqkv[256 + col];
  #pragma unroll
  for (int m = 0; m < MT; ++m) {
    int r0 = m * 16 + ((l >> 4) << 2);
    #pragma unroll
    for (int j = 0; j < 4; ++j) {
      int r = r0 + j;
      sQ[r * 256 + (((col << 1) ^ ((r & 7) << 4)) >> 1)] = f2b((accQ[m][j] + biasQ) * qscale);
      sK[r * 256 + (((col << 1) ^ ((r & 7) << 4)) >> 1)] = f2b(accK[m][j] + biasK);
    }
  }
}

// Paired-small body, templated on the item's TRUE mt class (1 or 2).
// Barrier sequence identical for MT=1 and MT=2 (all __syncthreads
// unconditional) so the two 8-wave halves of a block may run different MT.
// 76KB LDS half; KVP=32 V^T slots.
template<int MT>
__device__ __forceinline__ void small_body(
    unsigned short* sX, unsigned short* sQ, unsigned short* sK,
    float* sS, unsigned short* sP,
    const float* __restrict__ embed, const int* __restrict__ gidx,
    const float* __restrict__ b1, const float* __restrict__ b2,
    const float* __restrict__ ln1g, const float* __restrict__ ln1b,
    const float* __restrict__ bqkv, const float* __restrict__ bo,
    const float* __restrict__ ln2g, const float* __restrict__ ln2b,
    const unsigned short* __restrict__ w1f, const unsigned short* __restrict__ w2f,
    const unsigned short* __restrict__ wqkvf, const unsigned short* __restrict__ wof,
    float* __restrict__ out, int ht, int ws, int l, int item, int len) {

  constexpr int ROWS = 16 * MT;

  // ---- phase 0: gather rows [0, ROWS) (zeros beyond len) ----
  {
    int sub = ht >> 7;           // 0..3
    int c0 = (ht & 127) << 2;
    #pragma unroll 2
    for (int it = 0; it < 4 * MT; ++it) {
      int r = it * 4 + sub;
      float4 v = make_float4(0.f, 0.f, 0.f, 0.f);
      if (r <= len) {
        int row = gidx[item * K_S + r];
        v = *(const float4*)(embed + (size_t)row * K_D + c0);
      }
      ushort4v o;
      o[0] = f2b(v.x); o[1] = f2b(v.y); o[2] = f2b(v.z); o[3] = f2b(v.w);
      *(ushort4v*)(sX + r * 512 + (((c0 << 1) ^ ((r & 7) << 4)) >> 1)) = o;
    }
  }
  __syncthreads();

  // ---- phase 1: FF1 (two NT=1 passes, 2 n-tiles per wave) ----
  #pragma unroll 1
  for (int p = 0; p < 2; ++p) {
    int nt = ws * 2 + p;
    float4v acc[MT];
    #pragma unroll
    for (int i = 0; i < MT; ++i) acc[i] = (float4v){0.f,0.f,0.f,0.f};
    mmN<1, 16, MT, 2, 1>(sX, 512, (const bf16x8*)w1f, nt, 16, l, acc);
    int col = nt * 16 + (l & 15);
    float bias = b1[col];
    #pragma unroll
    for (int m = 0; m < MT; ++m) {
      int r0 = m * 16 + ((l >> 4) << 2);
      #pragma unroll
      for (int j = 0; j < 4; ++j) {
        int r = r0 + j;
        sQ[r * 256 + (((col << 1) ^ ((r & 7) << 4)) >> 1)] = f2b(fmaxf(acc[m][j] + bias, 0.f));
      }
    }
  }
  __syncthreads();

  // ---- phase 2: FF2 (two NT=2 passes) + residual ----
  #pragma unroll 1
  for (int p = 0; p < 2; ++p) {
    float4v acc[2 * MT];
    #pragma unroll
    for (int i = 0; i < 2 * MT; ++i) acc[i] = (float4v){0.f,0.f,0.f,0.f};
    mmN<2, 8, MT, 2, 1>(sQ, 256, (const bf16x8*)w2f, ws * 4 + p * 2, 8, l, acc);
    #pragma unroll
    for (int n = 0; n < 2; ++n) {
      int col = (ws * 4 + p * 2 + n) * 16 + (l & 15);
      float bias = b2[col];
      #pragma unroll
      for (int m = 0; m < MT; ++m) {
        int r0 = m * 16 + ((l >> 4) << 2);
        #pragma unroll
        for (int j = 0; j < 4; ++j) {
          int r = r0 + j;
          int e = r * 512 + (((col << 1) ^ ((r & 7) << 4)) >> 1);
          sX[e] = f2b(acc[m * 2 + n][j] + bias + b2f(sX[e]));
        }
      }
    }
  }
  __syncthreads();
  ln_pass<8>(sX, ln1g, ln1b, ws, l, ROWS);
  __syncthreads();

  // ---- phase 3: fused QKV (two triplet sub-passes); V kept in regs ----
  float4v accV0[MT], accV1[MT];
  qkv_pass<MT>(sX, wqkvf, ws * 2 + 0, l, sQ, sK, bqkv, accV0);
  qkv_pass<MT>(sX, wqkvf, ws * 2 + 1, l, sQ, sK, bqkv, accV1);
  __syncthreads();

  // ---- phase 4: scores; MT=1: 1 tile (wave 0), MT=2: 4 tiles (waves 0..3) ----
  {
    bool doS;
    int m0, n0;
    if constexpr (MT == 1) { doS = (ws == 0); m0 = 0; n0 = 0; }
    else                   { doS = (ws < 4); m0 = (ws >> 1) * 16; n0 = (ws & 1) * 16; }
    if (doS) {
      float4v acc = (float4v){0.f,0.f,0.f,0.f};
      bf16x8 b0 = ldfrag(sK, 256, n0, 0, l),  aq0 = ldfrag(sQ, 256, m0, 0, l);
      bf16x8 b1 = ldfrag(sK, 256, n0, 32, l), aq1 = ldfrag(sQ, 256, m0, 32, l);
      #pragma unroll 1
      for (int kt = 0; kt < 8; kt += 2) {
        acc = mfma16(aq0, b0, acc);
        if (kt + 2 < 8) { b0 = ldfrag(sK, 256, n0, (kt + 2) * 32, l); aq0 = ldfrag(sQ, 256, m0, (kt + 2) * 32, l); }
        acc = mfma16(aq1, b1, acc);
        if (kt + 3 < 8) { b1 = ldfrag(sK, 256, n0, (kt + 3) * 32, l); aq1 = ldfrag(sQ, 256, m0, (kt + 3) * 32, l); }
      }
      int col = n0 + (l & 15);
      int r0 = m0 + ((l >> 4) << 2);
      #pragma unroll
      for (int j = 0; j < 4; ++j) {
        int r = r0 + j;
        sS[r * 64 + (((col << 2) ^ ((r & 7) << 4)) >> 2)] = acc[j];
      }
    }
  }
  __syncthreads();

  // ---- phase 5: softmax (rows < ROWS) -> sP; V^T -> sK (KVP=32, SWM=3) ----
  {
    const bool valid = (l <= len);
    #pragma unroll 1
    for (int r = ws; r < ROWS; r += 8) {
      float s = valid ? sS[r * 64 + (((l << 2) ^ ((r & 7) << 4)) >> 2)] : -1e30f;
      float mx = s;
      #pragma unroll
      for (int off = 1; off < 64; off <<= 1) mx = fmaxf(mx, __shfl_xor(mx, off));
      float p = valid ? __expf(s - mx) : 0.f;
      float sum = p;
      #pragma unroll
      for (int off = 1; off < 64; off <<= 1) sum += __shfl_xor(sum, off);
      sP[r * 64 + (((l << 1) ^ ((r & 7) << 4)) >> 1)] = f2b(p / sum);
    }
    #pragma unroll
    for (int p = 0; p < 2; ++p) {
      int c = (ws * 2 + p) * 16 + (l & 15);
      float biasV = bqkv[512 + c];
      const float4v* aV = p ? accV1 : accV0;
      #pragma unroll
      for (int m = 0; m < MT; ++m) {
        int r0 = m * 16 + ((l >> 4) << 2);
        ushort4v o;
        #pragma unroll
        for (int j = 0; j < 4; ++j) o[j] = f2b(aV[m][j] + biasV);
        *(ushort4v*)(sK + c * 32 + (((r0 << 1) ^ ((c & 3) << 4)) >> 1)) = o;
      }
      #pragma unroll
      for (int m = MT; m < 2; ++m) {
        int r0 = m * 16 + ((l >> 4) << 2);
        ushort4v o; o[0] = 0; o[1] = 0; o[2] = 0; o[3] = 0;
        *(ushort4v*)(sK + c * 32 + (((r0 << 1) ^ ((c & 3) << 4)) >> 1)) = o;
      }
    }
  }
  __syncthreads();

  // ---- phase 7: ctx = P @ V (2 n-tiles, P loaded once) -> sQ ----
  {
    bf16x8 pa[MT];
    #pragma unroll
    for (int m = 0; m < MT; ++m) pa[m] = ldfrag(sP, 64, m * 16, 0, l);
    bf16x8 bf0 = ldfragm(sK, 32, (ws * 2 + 0) * 16, 0, l, 3);
    bf16x8 bf1 = ldfragm(sK, 32, (ws * 2 + 1) * 16, 0, l, 3);
    float4v z = (float4v){0.f,0.f,0.f,0.f};
    #pragma unroll
    for (int p = 0; p < 2; ++p) {
      const bf16x8& bfr = p ? bf1 : bf0;
      int col = (ws * 2 + p) * 16 + (l & 15);
      #pragma unroll
      for (int m = 0; m < MT; ++m) {
        float4v cc = mfma16(pa[m], bfr, z);
        int r0 = m * 16 + ((l >> 4) << 2);
        #pragma unroll
        for (int j = 0; j < 4; ++j) {
          int r = r0 + j;
          sQ[r * 256 + (((col << 1) ^ ((r & 7) << 4)) >> 1)] = f2b(cc[j]);
        }
      }
    }
  }
  __syncthreads();

  // ---- phase 8: Wo (two NT=2 passes) + residual ----
  #pragma unroll 1
  for (int p = 0; p < 2; ++p) {
    float4v acc[2 * MT];
    #pragma unroll
    for (int i = 0; i < 2 * MT; ++i) acc[i] = (float4v){0.f,0.f,0.f,0.f};
    mmN<2, 8, MT, 2, 1>(sQ, 256, (const bf16x8*)wof, ws * 4 + p * 2, 8, l, acc);
    #pragma unroll
    for (int n = 0; n < 2; ++n) {
      int col = (ws * 4 + p * 2 + n) * 16 + (l & 15);
      float bias = bo[col];
      #pragma unroll
      for (int m = 0; m < MT; ++m) {
        int r0 = m * 16 + ((l >> 4) << 2);
        #pragma unroll
        for (int j = 0; j < 4; ++j) {
          int r = r0 + j;
          int e = r * 512 + (((col << 1) ^ ((r & 7) << 4)) >> 1);
          sX[e] = f2b(acc[m * 2 + n][j] + bias + b2f(sX[e]));
        }
      }
    }
  }
  __syncthreads();
  ln_pass<8>(sX, ln2g, ln2b, ws, l, ROWS);
  __syncthreads();

  // ---- phase 9: masked mean pool (one col per thread, serial rows) ----
  {
    float sum = 0.f;
    for (int s = 0; s <= len; ++s)
      sum += b2f(sX[s * 512 + (((ht << 1) ^ ((s & 7) << 4)) >> 1)]);
    out[(size_t)item * K_D + ht] = sum / (float)(len + 1);
  }
}

// R11-structure big body (MT=3/4), full 152KB layout.
template<int MT>
__device__ __forceinline__ void big_body(
    unsigned short* sX, unsigned short* sQ, unsigned short* sK,
    float* sS, unsigned short* sP,
    const float* __restrict__ embed, const int* __restrict__ gidx,
    const float* __restrict__ b1, const float* __restrict__ b2,
    const float* __restrict__ ln1g, const float* __restrict__ ln1b,
    const float* __restrict__ bqkv, const float* __restrict__ bo,
    const float* __restrict__ ln2g, const float* __restrict__ ln2b,
    const unsigned short* __restrict__ w1f, const unsigned short* __restrict__ w2f,
    const unsigned short* __restrict__ wqkvf, const unsigned short* __restrict__ wof,
    float* __restrict__ out, int tid, int w, int l, int item, int len) {

  constexpr int ROWS = 16 * MT;
  constexpr int S2 = (MT <= 3) ? 2 : 1;
  constexpr int AP1 = (MT <= 3) ? 1 : 0;

  {
    const int sub = tid >> 7;
    const int c0 = (tid & 127) << 2;
    #pragma unroll 2
    for (int it = 0; it < 2 * MT; ++it) {
      int r = it * 8 + sub;
      float4 v = make_float4(0.f, 0.f, 0.f, 0.f);
      if (r <= len) {
        int row = gidx[item * K_S + r];
        v = *(const float4*)(embed + (size_t)row * K_D + c0);
      }
      ushort4v o;
      o[0] = f2b(v.x); o[1] = f2b(v.y); o[2] = f2b(v.z); o[3] = f2b(v.w);
      *(ushort4v*)(sX + r * 512 + (((c0 << 1) ^ ((r & 7) << 4)) >> 1)) = o;
    }
  }
  __syncthreads();

  {
    float4v acc[MT];
    #pragma unroll
    for (int i = 0; i < MT; ++i) acc[i] = (float4v){0.f,0.f,0.f,0.f};
    mmN<1, 16, MT, 2, AP1>(sX, 512, (const bf16x8*)w1f, w, 16, l, acc);
    int col = w * 16 + (l & 15);
    float bias = b1[col];
    #pragma unroll
    for (int m = 0; m < MT; ++m) {
      int r0 = m * 16 + ((l >> 4) << 2);
      #pragma unroll
      for (int j = 0; j < 4; ++j) {
        int r = r0 + j;
        sQ[r * 256 + (((col << 1) ^ ((r & 7) << 4)) >> 1)] = f2b(fmaxf(acc[m][j] + bias, 0.f));
      }
    }
  }
  __syncthreads();

  {
    float4v acc[2 * MT];
    #pragma unroll
    for (int i = 0; i < 2 * MT; ++i) acc[i] = (float4v){0.f,0.f,0.f,0.f};
    mmN<2, 8, MT, S2, 0>(sQ, 256, (const bf16x8*)w2f, w * 2, 8, l, acc);
    #pragma unroll
    for (int n = 0; n < 2; ++n) {
      int col = (w * 2 + n) * 16 + (l & 15);
      float bias = b2[col];
      #pragma unroll
      for (int m = 0; m < MT; ++m) {
        int r0 = m * 16 + ((l >> 4) << 2);
        #pragma unroll
        for (int j = 0; j < 4; ++j) {
          int r = r0 + j;
          int e = r * 512 + (((col << 1) ^ ((r & 7) << 4)) >> 1);
          sX[e] = f2b(acc[m * 2 + n][j] + bias + b2f(sX[e]));
        }
      }
    }
  }
  __syncthreads();
  ln_pass<16>(sX, ln1g, ln1b, w, l, ROWS);
  __syncthreads();

  {
    const bf16x8* Wf = (const bf16x8*)wqkvf;
    float4v accQ[MT], accK[MT];
    #pragma unroll
    for (int i = 0; i < MT; ++i) {
      accQ[i] = (float4v){0.f,0.f,0.f,0.f};
      accK[i] = (float4v){0.f,0.f,0.f,0.f};
    }
    const size_t baseQ = (size_t)(w) * 16 * 64 + l;
    const size_t baseK = (size_t)(16 + w) * 16 * 64 + l;
    bf16x8 q0 = Wf[baseQ], k0 = Wf[baseK];
    #pragma unroll 1
    for (int kt = 0; kt < 16; ++kt) {
      bf16x8 a[MT];
      #pragma unroll
      for (int m = 0; m < MT; ++m) a[m] = ldfrag(sX, 512, m * 16, kt * 32, l);
      #pragma unroll
      for (int m = 0; m < MT; ++m) accQ[m] = mfma16(a[m], q0, accQ[m]);
      #pragma unroll
      for (int m = 0; m < MT; ++m) accK[m] = mfma16(a[m], k0, accK[m]);
      if (kt + 1 < 16) {
        q0 = Wf[baseQ + (size_t)(kt + 1) * 64];
        k0 = Wf[baseK + (size_t)(kt + 1) * 64];
      }
    }
    const float qscale = 0.044194173824159216f;
    int col = w * 16 + (l & 15);
    float biasQ = bqkv[col];
    float biasK = bqkv[256 + col];
    #pragma unroll
    for (int m = 0; m < MT; ++m) {
      int r0 = m * 16 + ((l >> 4) << 2);
      #pragma unroll
      for (int j = 0; j < 4; ++j) {
        int r = r0 + j;
        sQ[r * 256 + (((col << 1) ^ ((r & 7) << 4)) >> 1)] = f2b((accQ[m][j] + biasQ) * qscale);
        sK[r * 256 + (((col << 1) ^ ((r & 7) << 4)) >> 1)] = f2b(accK[m][j] + biasK);
      }
    }
  }
  __syncthreads();

  if ((w >> 2) < MT) {
    float4v acc = (float4v){0.f,0.f,0.f,0.f};
    int n0 = (w & 3) * 16;
    int m0 = (w >> 2) * 16;
    bf16x8 b0 = ldfrag(sK, 256, n0, 0, l),  aq0 = ldfrag(sQ, 256, m0, 0, l);
    bf16x8 b1 = ldfrag(sK, 256, n0, 32, l), aq1 = ldfrag(sQ, 256, m0, 32, l);
    #pragma unroll 1
    for (int kt = 0; kt < 8; kt += 2) {
      acc = mfma16(aq0, b0, acc);
      if (kt + 2 < 8) { b0 = ldfrag(sK, 256, n0, (kt + 2) * 32, l); aq0 = ldfrag(sQ, 256, m0, (kt + 2) * 32, l); }
      acc = mfma16(aq1, b1, acc);
      if (kt + 3 < 8) { b1 = ldfrag(sK, 256, n0, (kt + 3) * 32, l); aq1 = ldfrag(sQ, 256, m0, (kt + 3) * 32, l); }
    }
    int col = n0 + (l & 15);
    int r0 = m0 + ((l >> 4) << 2);
    #pragma unroll
    for (int j = 0; j < 4; ++j) {
      int r = r0 + j;
      sS[r * 64 + (((col << 2) ^ ((r & 7) << 4)) >> 2)] = acc[j];
    }
  }
  float4v accV[MT];
  {
    #pragma unroll
    for (int i = 0; i < MT; ++i) accV[i] = (float4v){0.f,0.f,0.f,0.f};
    mmN<1, 16, MT, 2, AP1>(sX, 512, (const bf16x8*)wqkvf, 32 + w, 16, l, accV);
  }
  __syncthreads();

  {
    const bool valid = (l <= len);
    #pragma unroll 1
    for (int r = w; r < ROWS; r += 16) {
      float s = valid ? sS[r * 64 + (((l << 2) ^ ((r & 7) << 4)) >> 2)] : -1e30f;
      float mx = s;
      #pragma unroll
      for (int off = 1; off < 64; off <<= 1) mx = fmaxf(mx, __shfl_xor(mx, off));
      float p = valid ? __expf(s - mx) : 0.f;
      float sum = p;
      #pragma unroll
      for (int off = 1; off < 64; off <<= 1) sum += __shfl_xor(sum, off);
      sP[r * 64 + (((l << 1) ^ ((r & 7) << 4)) >> 1)] = f2b(p / sum);
    }
    int c = w * 16 + (l & 15);
    float biasV = bqkv[512 + c];
    #pragma unroll
    for (int m = 0; m < MT; ++m) {
      int r0 = m * 16 + ((l >> 4) << 2);
      ushort4v o;
      #pragma unroll
      for (int j = 0; j < 4; ++j) o[j] = f2b(accV[m][j] + biasV);
      *(ushort4v*)(sK + c * 64 + (((r0 << 1) ^ ((c & 7) << 4)) >> 1)) = o;
    }
    #pragma unroll
    for (int m = MT; m < 4; ++m) {
      int r0 = m * 16 + ((l >> 4) << 2);
      ushort4v o; o[0] = 0; o[1] = 0; o[2] = 0; o[3] = 0;
      *(ushort4v*)(sK + c * 64 + (((r0 << 1) ^ ((c & 7) << 4)) >> 1)) = o;
    }
  }
  __syncthreads();

  {
    float4v acc[MT];
    #pragma unroll
    for (int i = 0; i < MT; ++i) acc[i] = (float4v){0.f,0.f,0.f,0.f};
    #pragma unroll
    for (int kt = 0; kt < 2; ++kt) {
      bf16x8 bfr = ldfragm(sK, 64, w * 16, kt * 32, l, 7);
      #pragma unroll
      for (int m = 0; m < MT; ++m) {
        bf16x8 a = ldfrag(sP, 64, m * 16, kt * 32, l);
        acc[m] = mfma16(a, bfr, acc[m]);
      }
    }
    int col = w * 16 + (l & 15);
    #pragma unroll
    for (int m = 0; m < MT; ++m) {
      int r0 = m * 16 + ((l >> 4) << 2);
      #pragma unroll
      for (int j = 0; j < 4; ++j) {
        int r = r0 + j;
        sQ[r * 256 + (((col << 1) ^ ((r & 7) << 4)) >> 1)] = f2b(acc[m][j]);
      }
    }
  }
  __syncthreads();

  {
    float4v acc[2 * MT];
    #pragma unroll
    for (int i = 0; i < 2 * MT; ++i) acc[i] = (float4v){0.f,0.f,0.f,0.f};
    mmN<2, 8, MT, S2, 0>(sQ, 256, (const bf16x8*)wof, w * 2, 8, l, acc);
    #pragma unroll
    for (int n = 0; n < 2; ++n) {
      int col = (w * 2 + n) * 16 + (l & 15);
      float bias = bo[col];
      #pragma unroll
      for (int m = 0; m < MT; ++m) {
        int r0 = m * 16 + ((l >> 4) << 2);
        #pragma unroll
        for (int j = 0; j < 4; ++j) {
          int r = r0 + j;
          int e = r * 512 + (((col << 1) ^ ((r & 7) << 4)) >> 1);
          sX[e] = f2b(acc[m * 2 + n][j] + bias + b2f(sX[e]));
        }
      }
    }
  }
  __syncthreads();
  ln_pass<16>(sX, ln2g, ln2b, w, l, ROWS);
  __syncthreads();

  {
    int col = tid & 511;
    int half = tid >> 9;
    float sum = 0.f;
    for (int s = half; s <= len; s += 2)
      sum += b2f(sX[s * 512 + (((col << 1) ^ ((s & 7) << 4)) >> 1)]);
    if (half) sS[col] = sum;
    __syncthreads();
    if (!half) out[(size_t)item * K_D + col] = (sum + sS[col]) / (float)(len + 1);
  }
}

__global__ __launch_bounds__(1024, 4)
void fused_all(
    const float* __restrict__ embed, const int* __restrict__ gidx,
    const int* __restrict__ lengths,
    const float* __restrict__ b1, const float* __restrict__ b2,
    const float* __restrict__ ln1g, const float* __restrict__ ln1b,
    const float* __restrict__ bqkv, const float* __restrict__ bo,
    const float* __restrict__ ln2g, const float* __restrict__ ln2b,
    const unsigned short* __restrict__ w1f, const unsigned short* __restrict__ w2f,
    const unsigned short* __restrict__ wqkvf, const unsigned short* __restrict__ wof,
    const int* __restrict__ lists, const int* __restrict__ meta,
    float* __restrict__ out) {
  __shared__ unsigned char lds[155648];

  const int tid = (int)threadIdx.x;
  const int w = tid >> 6;
  const int l = tid & 63;
  const int j = (int)blockIdx.x;
  const int n1 = meta[0];
  const int n2 = meta[1];
  const int nbig = meta[2];
  const int p1 = (n1 + 1) >> 1;
  const int p2 = (n2 + 1) >> 1;

  if (j < p1 + p2) {
    // paired-small region: same-class pairs (mt1 pairs first, then mt2)
    const bool m1 = (j < p1);
    const int base = m1 ? 0 : 4096;
    const int cnt = m1 ? n1 : n2;
    const int jj = m1 ? j : j - p1;
    int i0 = lists[base + 2 * jj];
    int i1 = (2 * jj + 1 < cnt) ? lists[base + 2 * jj + 1] : i0;  // dup: benign
    int h = w >> 3;
    int ws_ = w & 7;
    int ht = ws_ * 64 + l;
    int item = h ? i1 : i0;
    int len = lengths[item];
    size_t bo_ = (size_t)h * 77824;
    unsigned short* sX = (unsigned short*)(lds + bo_);
    unsigned short* sQ = (unsigned short*)(lds + bo_ + 32768);
    unsigned short* sK = (unsigned short*)(lds + bo_ + 49152);
    float* sS = (float*)(lds + bo_ + 65536);
    unsigned short* sP = (unsigned short*)(lds + bo_ + 73728);
    if (m1)
      small_body<1>(sX, sQ, sK, sS, sP, embed, gidx, b1, b2, ln1g, ln1b, bqkv, bo,
                    ln2g, ln2b, w1f, w2f, wqkvf, wof, out, ht, ws_, l, item, len);
    else
      small_body<2>(sX, sQ, sK, sS, sP, embed, gidx, b1, b2, ln1g, ln1b, bqkv, bo,
                    ln2g, ln2b, w1f, w2f, wqkvf, wof, out, ht, ws_, l, item, len);
  } else {
    int bi = j - (p1 + p2);
    if (bi >= nbig) return;
    int item = lists[8192 + bi];
    int len = lengths[item];
    int mt = (len + 16) >> 4;
    unsigned short* sX = (unsigned short*)lds;
    unsigned short* sQ = (unsigned short*)(lds + 65536);
    unsigned short* sK = (unsigned short*)(lds + 98304);
    float* sS = (float*)(lds + 131072);
    unsigned short* sP = (unsigned short*)(lds + 147456);
    if (mt == 3)
      big_body<3>(sX, sQ, sK, sS, sP, embed, gidx, b1, b2, ln1g, ln1b, bqkv, bo,
                  ln2g, ln2b, w1f, w2f, wqkvf, wof, out, tid, w, l, item, len);
    else
      big_body<4>(sX, sQ, sK, sS, sP, embed, gidx, b1, b2, ln1g, ln1b, bqkv, bo,
                  ln2g, ln2b, w1f, w2f, wqkvf, wof, out, tid, w, l, item, len);
  }
}

extern "C" void kernel_launch(void* const* d_in, const int* in_sizes, int n_in,
                              void* d_out, int out_size, void* d_ws, size_t ws_size,
                              hipStream_t stream) {
  (void)in_sizes; (void)n_in; (void)out_size; (void)ws_size;
  const float* embed = (const float*)d_in[0];
  const int* idx = (const int*)d_in[1];
  const int* lengths = (const int*)d_in[2];
  const float* W1 = (const float*)d_in[3];
  const float* b1 = (const float*)d_in[4];
  const float* W2 = (const float*)d_in[5];
  const float* b2 = (const float*)d_in[6];
  const float* ln1g = (const float*)d_in[7];
  const float* ln1b = (const float*)d_in[8];
  const float* Wqkv = (const float*)d_in[9];
  const float* bqkv = (const float*)d_in[10];
  const float* Wo = (const float*)d_in[11];
  const float* bo = (const float*)d_in[12];
  const float* ln2g = (const float*)d_in[13];
  const float* ln2b = (const float*)d_in[14];

  unsigned short* ws = (unsigned short*)d_ws;
  unsigned short* w1f = ws;                 // 131072 bf16
  unsigned short* w2f = ws + 131072;        // 131072
  unsigned short* wqkvf = ws + 262144;      // 393216
  unsigned short* wof = ws + 655360;        // 131072  -> ends at 786432
  int* lists = (int*)(ws + 786432);         // 12288 ints
  int* meta = lists + 12288;                // 3 ints

  prep_weights<<<64, 256, 0, stream>>>(W1, w1f, 512, 256);
  prep_weights<<<64, 256, 0, stream>>>(W2, w2f, 256, 512);
  prep_weights<<<192, 256, 0, stream>>>(Wqkv, wqkvf, 512, 768);
  prep_weights<<<64, 256, 0, stream>>>(Wo, wof, 256, 512);
  zero_meta<<<1, 64, 0, stream>>>(meta);
  bucket<<<16, 256, 0, stream>>>(lengths, lists, meta);

  fused_all<<<4608, 1024, 0, stream>>>(embed, idx, lengths, b1, b2, ln1g, ln1b,
                                       bqkv, bo, ln2g, ln2b, w1f, w2f, wqkvf, wof,
                                       lists, meta, (float*)d_out);
}